// Round 8
// baseline (753.470 us; speedup 1.0000x reference)
//
#include <hip/hip_runtime.h>
#include <hip/hip_bf16.h>

// RGCN 2-layer forward, f32 accuracy. CSR counting-sort; layer-1 GEMM via
// split-bf16 (hi+lo) 3-term MFMA, split-K=2, BM=64, packed hi/lo A layout.
// L1: aggP[seg][4][2][32] = bf16-split mean x[src] (hi/lo interleaved per 32-chunk);
//     part[kq] = [agg|x]_kq @ [W1;Wr1]_kq  (MFMA, 1564 blocks)
// L2: hv = relu(part0+part1+b1) folded into t[n,0:18] = hv @ [W2_r(:,0:2).. | Wr2];
//     out = sum_r mean t[src,2r:2r+2] + t[n,16:18] + b2.

#define NR 8
#define DH 128
#define KCH 18  // kc chunks (32-wide) per split-K block; 36 total

typedef short short8 __attribute__((ext_vector_type(8)));
typedef float f32x4 __attribute__((ext_vector_type(4)));

__device__ inline ushort f2bf(float v) {
  __hip_bfloat16 b = __float2bfloat16(v);
  return *reinterpret_cast<ushort*>(&b);
}
__device__ inline float bf2f(ushort u) {
  __hip_bfloat16 b;
  *reinterpret_cast<ushort*>(&b) = u;
  return __bfloat162float(b);
}
union U128 { uint4 u; short8 s; };

// ---------- counting sort ----------
__global__ __launch_bounds__(256) void k_hist(const int* __restrict__ dst, const int* __restrict__ et,
                                              int* __restrict__ hist, int E) {
  int e = blockIdx.x * 256 + threadIdx.x;
  if (e < E) atomicAdd(&hist[dst[e] * NR + et[e]], 1);
}

__global__ __launch_bounds__(256) void k_scan_local(const int* __restrict__ hist, int* __restrict__ offs,
                                                    int* __restrict__ blksum, int S) {
  __shared__ int tsum[256];
  int tid = threadIdx.x;
  int base = blockIdx.x * 1024 + tid * 4;
  int v[4], tot = 0;
  #pragma unroll
  for (int i = 0; i < 4; i++) { v[i] = (base + i < S) ? hist[base + i] : 0; tot += v[i]; }
  tsum[tid] = tot;
  __syncthreads();
  for (int off = 1; off < 256; off <<= 1) {
    int val = tsum[tid];
    int add = (tid >= off) ? tsum[tid - off] : 0;
    __syncthreads();
    tsum[tid] = val + add;
    __syncthreads();
  }
  int run = tsum[tid] - tot;
  #pragma unroll
  for (int i = 0; i < 4; i++) {
    if (base + i < S) offs[base + i] = run;
    run += v[i];
  }
  if (tid == 255) blksum[blockIdx.x] = tsum[255];
}

__global__ __launch_bounds__(512) void k_scan_blk(const int* __restrict__ blksum, int* __restrict__ blkoff, int NB) {
  __shared__ int s[512];
  int tid = threadIdx.x;
  int v = (tid < NB) ? blksum[tid] : 0;
  s[tid] = v;
  __syncthreads();
  for (int off = 1; off < 512; off <<= 1) {
    int val = s[tid];
    int add = (tid >= off) ? s[tid - off] : 0;
    __syncthreads();
    s[tid] = val + add;
    __syncthreads();
  }
  if (tid < NB) blkoff[tid] = s[tid] - v;
}

__global__ __launch_bounds__(256) void k_scan_add(int* __restrict__ offs, const int* __restrict__ blkoff, int S) {
  int tid = threadIdx.x;
  int base = blockIdx.x * 1024 + tid * 4;
  int add = blkoff[blockIdx.x];
  #pragma unroll
  for (int i = 0; i < 4; i++)
    if (base + i < S) offs[base + i] += add;
}

__global__ __launch_bounds__(256) void k_scatter_idx(const int* __restrict__ src, const int* __restrict__ dst,
                                                     const int* __restrict__ et, int* __restrict__ offs,
                                                     int* __restrict__ sorted_src, int E) {
  int e = blockIdx.x * 256 + threadIdx.x;
  if (e >= E) return;
  int seg = dst[e] * NR + et[e];
  int pos = atomicAdd(&offs[seg], 1);
  sorted_src[pos] = src[e];
}

// ---------- W split+transpose: Wt[col][k], k in [0,1152) ----------
__global__ __launch_bounds__(128) void k_wsplit(const float* __restrict__ W1, const float* __restrict__ Wr1,
                                                ushort* __restrict__ WtH, ushort* __restrict__ WtL) {
  int c = blockIdx.x;
  int k = blockIdx.y * 128 + threadIdx.x;
  float v = (k < 1024) ? W1[(size_t)k * 128 + c] : Wr1[(size_t)(k - 1024) * 128 + c];
  ushort hi = f2bf(v);
  ushort lo = f2bf(v - bf2f(hi));
  WtH[(size_t)c * 1152 + k] = hi;
  WtL[(size_t)c * 1152 + k] = lo;
}

// ---------- layer 1 aggregate: packed hi/lo per 32-chunk: aggP[seg][c][plane][32] ----------
__global__ __launch_bounds__(256) void k_agg1(const int* __restrict__ offs, const int* __restrict__ hist,
                                              const int* __restrict__ sorted_src, const float* __restrict__ x,
                                              ushort* __restrict__ aggP, int S) {
  int tid = threadIdx.x;
  int seg = blockIdx.x * 4 + (tid >> 6);
  int lane = tid & 63;
  if (seg >= S) return;
  int end = offs[seg];
  int cnt = hist[seg];
  int st = end - cnt;
  float ax = 0.f, ay = 0.f;
  int i = st;
  for (; i + 4 <= end; i += 4) {
    int s0 = sorted_src[i + 0];
    int s1 = sorted_src[i + 1];
    int s2 = sorted_src[i + 2];
    int s3 = sorted_src[i + 3];
    float2 v0 = *(const float2*)(x + (size_t)s0 * DH + lane * 2);
    float2 v1 = *(const float2*)(x + (size_t)s1 * DH + lane * 2);
    float2 v2 = *(const float2*)(x + (size_t)s2 * DH + lane * 2);
    float2 v3 = *(const float2*)(x + (size_t)s3 * DH + lane * 2);
    ax += (v0.x + v1.x) + (v2.x + v3.x);
    ay += (v0.y + v1.y) + (v2.y + v3.y);
  }
  for (; i < end; i++) {
    int s = sorted_src[i];
    float2 v = *(const float2*)(x + (size_t)s * DH + lane * 2);
    ax += v.x;
    ay += v.y;
  }
  float inv = 1.f / fmaxf((float)cnt, 1.f);
  ax *= inv;
  ay *= inv;
  ushort hx = f2bf(ax), hy = f2bf(ay);
  ushort lx = f2bf(ax - bf2f(hx)), ly = f2bf(ay - bf2f(hy));
  ushort2 hv; hv.x = hx; hv.y = hy;
  ushort2 lv; lv.x = lx; lv.y = ly;
  // lane covers k = {lane*2, lane*2+1}: chunk = lane>>4, pos = (lane*2)&31
  ushort* base = aggP + (size_t)seg * 256 + (lane >> 4) * 64 + ((lane * 2) & 31);
  *(ushort2*)(base) = hv;
  *(ushort2*)(base + 32) = lv;
}

// ---------- layer 1 MFMA GEMM, split-K=2, BM=64 ----------
// 256 thr = 4 waves (2 wr x 2 wc), block tile 64x128, wave tile 32x64 (2x4 frags).
// A-frags direct from global (hi+lo share a 128B line); 2-deep A prefetch.
// B staged in LDS with XOR-chunk swizzle. part[kq][n][c] = partial sums.
__global__ __launch_bounds__(256) void k_gemm1_mfma(
    const ushort* __restrict__ aggP, const float* __restrict__ xf,
    const ushort* __restrict__ WtH, const ushort* __restrict__ WtL,
    float* __restrict__ part, int N) {
  __shared__ ushort BsH[128 * 32];
  __shared__ ushort BsL[128 * 32];

  int tid = threadIdx.x;
  int w = tid >> 6, lane = tid & 63;
  int wr = w >> 1, wc = w & 1;
  int n0 = blockIdx.x * 64;
  int k0 = blockIdx.y * KCH;
  int kend = k0 + KCH;

  int frow = lane & 15;
  int g4 = lane >> 4;     // chunk group 0..3
  int fk8 = g4 * 8;

  // B staging: threads 0-127 hi plane, 128-255 lo plane; thread stages col sc's 32 k.
  int sp = tid >> 7;
  int sc = tid & 127;
  const ushort* wsrc = (sp ? WtL : WtH) + (size_t)sc * 1152;
  ushort* Bss = (sp ? BsL : BsH) + sc * 32;
  int sx = sc & 3;  // XOR key for chunk placement

  f32x4 acc[2][4];
  #pragma unroll
  for (int i = 0; i < 2; i++)
    #pragma unroll
    for (int j = 0; j < 4; j++) acc[i][j] = (f32x4){0.f, 0.f, 0.f, 0.f};

  uint4 praw[2][2][2];  // [buf][ft][plane/half]
  uint4 rb[4];
  short8 aH[2], aL[2];

  int arow[2];
  #pragma unroll
  for (int ft = 0; ft < 2; ft++) {
    int r = n0 + wr * 32 + ft * 16 + frow;
    arow[ft] = (r < N) ? r : (N - 1);  // clamp: OOB rows compute garbage, never stored
  }

  #define LOADA(kc, buf)                                                         \
    {                                                                            \
      if ((kc) < 32) {                                                           \
        _Pragma("unroll")                                                        \
        for (int ft = 0; ft < 2; ft++) {                                         \
          const ushort* p_ = aggP + (size_t)arow[ft] * 2048 + (kc) * 64 + fk8;   \
          praw[buf][ft][0] = *(const uint4*)(p_);                                \
          praw[buf][ft][1] = *(const uint4*)(p_ + 32);                           \
        }                                                                        \
      } else {                                                                   \
        _Pragma("unroll")                                                        \
        for (int ft = 0; ft < 2; ft++) {                                         \
          const uint4* xp = (const uint4*)(xf + (size_t)arow[ft] * 128 +         \
                                           ((kc) - 32) * 32 + fk8);              \
          praw[buf][ft][0] = xp[0];                                              \
          praw[buf][ft][1] = xp[1];                                              \
        }                                                                        \
      }                                                                          \
    }
  #define LOADB(kc)                                                              \
    {                                                                            \
      const uint4* ws_ = (const uint4*)(wsrc + (kc) * 32);                       \
      rb[0] = ws_[0]; rb[1] = ws_[1]; rb[2] = ws_[2]; rb[3] = ws_[3];            \
    }

  LOADA(k0, 0);
  LOADA(k0 + 1, 1);
  LOADB(k0);

  for (int kc = k0; kc < kend; kc++) {
    int cur = (kc - k0) & 1;
    // stage B with XOR-chunk placement: chunk i -> offset ((i^sx)*8)
    *(uint4*)(Bss + ((0 ^ sx) << 3)) = rb[0];
    *(uint4*)(Bss + ((1 ^ sx) << 3)) = rb[1];
    *(uint4*)(Bss + ((2 ^ sx) << 3)) = rb[2];
    *(uint4*)(Bss + ((3 ^ sx) << 3)) = rb[3];
    __syncthreads();

    // decode current A frags
    if (kc < 32) {
      #pragma unroll
      for (int ft = 0; ft < 2; ft++) {
        U128 uh, ul;
        uh.u = praw[cur][ft][0];
        ul.u = praw[cur][ft][1];
        aH[ft] = uh.s;
        aL[ft] = ul.s;
      }
    } else {
      #pragma unroll
      for (int ft = 0; ft < 2; ft++) {
        union { uint4 u[2]; float f[8]; } xx;
        xx.u[0] = praw[cur][ft][0];
        xx.u[1] = praw[cur][ft][1];
        short8 th, tl;
        #pragma unroll
        for (int j = 0; j < 8; j++) {
          ushort hb = f2bf(xx.f[j]);
          th[j] = (short)hb;
          tl[j] = (short)f2bf(xx.f[j] - bf2f(hb));
        }
        aH[ft] = th;
        aL[ft] = tl;
      }
    }

    if (kc + 2 < kend) LOADA(kc + 2, cur);
    if (kc + 1 < kend) LOADB(kc + 1);

    #pragma unroll
    for (int ct = 0; ct < 4; ct++) {
      int gcol = wc * 64 + ct * 16 + frow;
      int boff = gcol * 32 + ((g4 ^ (frow & 3)) << 3);  // matches staging XOR
      const short8 bH = *(const short8*)(BsH + boff);
      const short8 bL = *(const short8*)(BsL + boff);
      #pragma unroll
      for (int ft = 0; ft < 2; ft++) {
        acc[ft][ct] = __builtin_amdgcn_mfma_f32_16x16x32_bf16(aH[ft], bH, acc[ft][ct], 0, 0, 0);
        acc[ft][ct] = __builtin_amdgcn_mfma_f32_16x16x32_bf16(aH[ft], bL, acc[ft][ct], 0, 0, 0);
        acc[ft][ct] = __builtin_amdgcn_mfma_f32_16x16x32_bf16(aL[ft], bH, acc[ft][ct], 0, 0, 0);
      }
    }
    __syncthreads();
  }
  #undef LOADA
  #undef LOADB

  // epilogue: raw partial sums; D layout col=lane&15, row=(lane>>4)*4+q
  float* po = part + (size_t)blockIdx.y * N * DH;
  int rbase = n0 + wr * 32 + (lane >> 4) * 4;
  #pragma unroll
  for (int ft = 0; ft < 2; ft++) {
    #pragma unroll
    for (int ct = 0; ct < 4; ct++) {
      int C = wc * 64 + ct * 16 + frow;
      #pragma unroll
      for (int q = 0; q < 4; q++) {
        int R = rbase + ft * 16 + q;
        if (R < N) po[(size_t)R * DH + C] = acc[ft][ct][q];
      }
    }
  }
}

// ---------- layer-2 transform (fused split-K combine + bias + relu) ----------
__global__ __launch_bounds__(256) void k_l2trans(const float* __restrict__ part, const float* __restrict__ b1,
                                                 const float* __restrict__ W2, const float* __restrict__ Wr2,
                                                 float* __restrict__ t, int N) {
  __shared__ float Wt[18 * 128];
  int tid = threadIdx.x;
  for (int i = tid; i < 2304; i += 256) {
    float v; int oc, d;
    if (i < 2048) { int r = i >> 8, rem = i & 255; d = rem >> 1; int c = rem & 1; oc = r * 2 + c; v = W2[i]; }
    else { int i2 = i - 2048; d = i2 >> 1; int c = i2 & 1; oc = 16 + c; v = Wr2[i2]; }
    Wt[oc * 128 + d] = v;
  }
  __syncthreads();
  int node = blockIdx.x * 4 + (tid >> 6);
  int lane = tid & 63;
  if (node >= N) return;
  size_t NP = (size_t)N * DH;
  float2 a0 = *(const float2*)(part + (size_t)node * DH + lane * 2);
  float2 a1 = *(const float2*)(part + NP + (size_t)node * DH + lane * 2);
  float2 bb = *(const float2*)(b1 + lane * 2);
  float2 hv;
  hv.x = fmaxf(a0.x + a1.x + bb.x, 0.f);
  hv.y = fmaxf(a0.y + a1.y + bb.y, 0.f);
  #pragma unroll
  for (int oc = 0; oc < 18; oc++) {
    float2 w = *(const float2*)(Wt + oc * 128 + lane * 2);
    float p = hv.x * w.x + hv.y * w.y;
    p += __shfl_xor(p, 32); p += __shfl_xor(p, 16); p += __shfl_xor(p, 8);
    p += __shfl_xor(p, 4);  p += __shfl_xor(p, 2);  p += __shfl_xor(p, 1);
    if (lane == 0) t[(size_t)node * 18 + oc] = p;
  }
}

// ---------- output: gather tiny t values per segment ----------
__global__ __launch_bounds__(256) void k_out2(const int* __restrict__ offs, const int* __restrict__ hist,
                                              const int* __restrict__ sorted_src, const float* __restrict__ t,
                                              const float* __restrict__ b2, float* __restrict__ out, int N) {
  int n = blockIdx.x * 256 + threadIdx.x;
  if (n >= N) return;
  float o0 = t[(size_t)n * 18 + 16] + b2[0];
  float o1 = t[(size_t)n * 18 + 17] + b2[1];
  #pragma unroll
  for (int r = 0; r < NR; r++) {
    int seg = n * NR + r;
    int en = offs[seg], cc = hist[seg];
    float s0 = 0.f, s1 = 0.f;
    for (int i = en - cc; i < en; i++) {
      int s = sorted_src[i];
      s0 += t[(size_t)s * 18 + r * 2];
      s1 += t[(size_t)s * 18 + r * 2 + 1];
    }
    float inv = 1.f / fmaxf((float)cc, 1.f);
    o0 += s0 * inv;
    o1 += s1 * inv;
  }
  out[(size_t)n * 2 + 0] = o0;
  out[(size_t)n * 2 + 1] = o1;
}

extern "C" void kernel_launch(void* const* d_in, const int* in_sizes, int n_in,
                              void* d_out, int out_size, void* d_ws, size_t ws_size,
                              hipStream_t stream) {
  const float* x   = (const float*)d_in[0];
  const int*   ei  = (const int*)d_in[1];
  const int*   et  = (const int*)d_in[2];
  const float* W1  = (const float*)d_in[3];
  const float* Wr1 = (const float*)d_in[4];
  const float* b1  = (const float*)d_in[5];
  const float* W2  = (const float*)d_in[6];
  const float* Wr2 = (const float*)d_in[7];
  const float* b2  = (const float*)d_in[8];
  float* out = (float*)d_out;

  int E = in_sizes[1] / 2;
  int N = in_sizes[0] / DH;
  int S = N * NR;
  const int* src = ei;
  const int* dst = ei + E;

  // ws layout: ints | aggP (packed hi/lo) | WtH WtL | part(2*N*128 f32) | t
  int* hist       = (int*)d_ws;                  // S
  int* offs       = hist + S;                    // S
  int* blksum     = offs + S;                    // 1024
  int* blkoff     = blksum + 1024;               // 1024
  int* sorted_src = blkoff + 1024;               // E
  size_t int_elems = (size_t)S * 2 + 2048 + E;
  int_elems = (int_elems + 3) & ~(size_t)3;      // 16B align
  ushort* aggP = (ushort*)(hist + int_elems);    // S*256
  ushort* WtH  = aggP + (size_t)S * 256;         // 128*1152
  ushort* WtL  = WtH + 128 * 1152;               // 128*1152
  size_t ush_elems = (size_t)S * 256 + 2 * 128 * 1152;
  float* part = (float*)(aggP + ush_elems);      // 2*N*128
  float* t    = part + (size_t)2 * N * DH;       // N*18

  hipMemsetAsync(hist, 0, sizeof(int) * (size_t)S, stream);

  k_hist<<<(E + 255) / 256, 256, 0, stream>>>(dst, et, hist, E);

  int NB = (S + 1023) / 1024;
  k_scan_local<<<NB, 256, 0, stream>>>(hist, offs, blksum, S);
  k_scan_blk<<<1, 512, 0, stream>>>(blksum, blkoff, NB);
  k_scan_add<<<NB, 256, 0, stream>>>(offs, blkoff, S);

  k_scatter_idx<<<(E + 255) / 256, 256, 0, stream>>>(src, dst, et, offs, sorted_src, E);

  k_wsplit<<<dim3(128, 9), 128, 0, stream>>>(W1, Wr1, WtH, WtL);

  k_agg1<<<(S + 3) / 4, 256, 0, stream>>>(offs, hist, sorted_src, x, aggP, S);

  k_gemm1_mfma<<<dim3((N + 63) / 64, 2), 256, 0, stream>>>(aggP, x, WtH, WtL, part, N);

  k_l2trans<<<(N + 3) / 4, 256, 0, stream>>>(part, b1, W2, Wr2, t, N);

  k_out2<<<(N + 255) / 256, 256, 0, stream>>>(offs, hist, sorted_src, t, b2, out, N);
}

// Round 9
// 680.456 us; speedup vs baseline: 1.1073x; 1.1073x over previous
//
#include <hip/hip_runtime.h>
#include <hip/hip_bf16.h>

// RGCN 2-layer forward, f32 accuracy. CSR counting-sort; layer-1 GEMM via
// split-bf16 (hi+lo) 3-term MFMA, split-K=2, BM=128, packed hi/lo A layout.
// L1: aggP[seg][4ch][2pl][32] = bf16-split mean x[src] (hi/lo share 128B line);
//     part[kq] = [agg|x]_kq @ [W1;Wr1]_kq  (MFMA, 782 blocks: L2/L3-friendly)
// L2: hv = relu(part0+part1+b1) folded into t[n,0:18] = hv @ [W2_r(:,0:2).. | Wr2];
//     out = sum_r mean t[src,2r:2r+2] + t[n,16:18] + b2.

#define NR 8
#define DH 128
#define KCH 18  // kc chunks (32-wide) per split-K block; 36 total

typedef short short8 __attribute__((ext_vector_type(8)));
typedef float f32x4 __attribute__((ext_vector_type(4)));

__device__ inline ushort f2bf(float v) {
  __hip_bfloat16 b = __float2bfloat16(v);
  return *reinterpret_cast<ushort*>(&b);
}
__device__ inline float bf2f(ushort u) {
  __hip_bfloat16 b;
  *reinterpret_cast<ushort*>(&b) = u;
  return __bfloat162float(b);
}
union U128 { uint4 u; short8 s; };

// ---------- counting sort ----------
__global__ __launch_bounds__(256) void k_hist(const int* __restrict__ dst, const int* __restrict__ et,
                                              int* __restrict__ hist, int E) {
  int e = blockIdx.x * 256 + threadIdx.x;
  if (e < E) atomicAdd(&hist[dst[e] * NR + et[e]], 1);
}

__global__ __launch_bounds__(256) void k_scan_local(const int* __restrict__ hist, int* __restrict__ offs,
                                                    int* __restrict__ blksum, int S) {
  __shared__ int tsum[256];
  int tid = threadIdx.x;
  int base = blockIdx.x * 1024 + tid * 4;
  int v[4], tot = 0;
  #pragma unroll
  for (int i = 0; i < 4; i++) { v[i] = (base + i < S) ? hist[base + i] : 0; tot += v[i]; }
  tsum[tid] = tot;
  __syncthreads();
  for (int off = 1; off < 256; off <<= 1) {
    int val = tsum[tid];
    int add = (tid >= off) ? tsum[tid - off] : 0;
    __syncthreads();
    tsum[tid] = val + add;
    __syncthreads();
  }
  int run = tsum[tid] - tot;
  #pragma unroll
  for (int i = 0; i < 4; i++) {
    if (base + i < S) offs[base + i] = run;
    run += v[i];
  }
  if (tid == 255) blksum[blockIdx.x] = tsum[255];
}

__global__ __launch_bounds__(512) void k_scan_blk(const int* __restrict__ blksum, int* __restrict__ blkoff, int NB) {
  __shared__ int s[512];
  int tid = threadIdx.x;
  int v = (tid < NB) ? blksum[tid] : 0;
  s[tid] = v;
  __syncthreads();
  for (int off = 1; off < 512; off <<= 1) {
    int val = s[tid];
    int add = (tid >= off) ? s[tid - off] : 0;
    __syncthreads();
    s[tid] = val + add;
    __syncthreads();
  }
  if (tid < NB) blkoff[tid] = s[tid] - v;
}

__global__ __launch_bounds__(256) void k_scan_add(int* __restrict__ offs, const int* __restrict__ blkoff, int S) {
  int tid = threadIdx.x;
  int base = blockIdx.x * 1024 + tid * 4;
  int add = blkoff[blockIdx.x];
  #pragma unroll
  for (int i = 0; i < 4; i++)
    if (base + i < S) offs[base + i] += add;
}

__global__ __launch_bounds__(256) void k_scatter_idx(const int* __restrict__ src, const int* __restrict__ dst,
                                                     const int* __restrict__ et, int* __restrict__ offs,
                                                     int* __restrict__ sorted_src, int E) {
  int e = blockIdx.x * 256 + threadIdx.x;
  if (e >= E) return;
  int seg = dst[e] * NR + et[e];
  int pos = atomicAdd(&offs[seg], 1);
  sorted_src[pos] = src[e];
}

// ---------- W split+transpose: Wt[col][k], k in [0,1152) ----------
__global__ __launch_bounds__(128) void k_wsplit(const float* __restrict__ W1, const float* __restrict__ Wr1,
                                                ushort* __restrict__ WtH, ushort* __restrict__ WtL) {
  int c = blockIdx.x;
  int k = blockIdx.y * 128 + threadIdx.x;
  float v = (k < 1024) ? W1[(size_t)k * 128 + c] : Wr1[(size_t)(k - 1024) * 128 + c];
  ushort hi = f2bf(v);
  ushort lo = f2bf(v - bf2f(hi));
  WtH[(size_t)c * 1152 + k] = hi;
  WtL[(size_t)c * 1152 + k] = lo;
}

// ---------- layer 1 aggregate: packed hi/lo per 32-chunk: aggP[seg][c][plane][32] ----------
__global__ __launch_bounds__(256) void k_agg1(const int* __restrict__ offs, const int* __restrict__ hist,
                                              const int* __restrict__ sorted_src, const float* __restrict__ x,
                                              ushort* __restrict__ aggP, int S) {
  int tid = threadIdx.x;
  int seg = blockIdx.x * 4 + (tid >> 6);
  int lane = tid & 63;
  if (seg >= S) return;
  int end = offs[seg];
  int cnt = hist[seg];
  int st = end - cnt;
  float ax = 0.f, ay = 0.f;
  int i = st;
  for (; i + 4 <= end; i += 4) {
    int s0 = sorted_src[i + 0];
    int s1 = sorted_src[i + 1];
    int s2 = sorted_src[i + 2];
    int s3 = sorted_src[i + 3];
    float2 v0 = *(const float2*)(x + (size_t)s0 * DH + lane * 2);
    float2 v1 = *(const float2*)(x + (size_t)s1 * DH + lane * 2);
    float2 v2 = *(const float2*)(x + (size_t)s2 * DH + lane * 2);
    float2 v3 = *(const float2*)(x + (size_t)s3 * DH + lane * 2);
    ax += (v0.x + v1.x) + (v2.x + v3.x);
    ay += (v0.y + v1.y) + (v2.y + v3.y);
  }
  for (; i < end; i++) {
    int s = sorted_src[i];
    float2 v = *(const float2*)(x + (size_t)s * DH + lane * 2);
    ax += v.x;
    ay += v.y;
  }
  float inv = 1.f / fmaxf((float)cnt, 1.f);
  ax *= inv;
  ay *= inv;
  ushort hx = f2bf(ax), hy = f2bf(ay);
  ushort lx = f2bf(ax - bf2f(hx)), ly = f2bf(ay - bf2f(hy));
  ushort2 hv; hv.x = hx; hv.y = hy;
  ushort2 lv; lv.x = lx; lv.y = ly;
  // lane covers k = {lane*2, lane*2+1}: chunk = lane>>4, pos = (lane*2)&31
  ushort* base = aggP + (size_t)seg * 256 + (lane >> 4) * 64 + ((lane * 2) & 31);
  *(ushort2*)(base) = hv;
  *(ushort2*)(base + 32) = lv;
}

// ---------- layer 1 MFMA GEMM, split-K=2, BM=128 ----------
// 256 thr = 4 waves (2 wr x 2 wc), block tile 128x128, wave tile 64x64 (4x4 frags).
// A-frags direct from global (hi+lo share one 128B line, packed layout);
// 2-deep A prefetch. B staged in LDS with XOR-chunk swizzle.
// part[kq][n][c] = partial sums (no bias/relu).
__global__ __launch_bounds__(256) void k_gemm1_mfma(
    const ushort* __restrict__ aggP, const float* __restrict__ xf,
    const ushort* __restrict__ WtH, const ushort* __restrict__ WtL,
    float* __restrict__ part, int N) {
  __shared__ ushort BsH[128 * 32];
  __shared__ ushort BsL[128 * 32];

  int tid = threadIdx.x;
  int w = tid >> 6, lane = tid & 63;
  int wr = w >> 1, wc = w & 1;
  int n0 = blockIdx.x * 128;
  int k0 = blockIdx.y * KCH;
  int kend = k0 + KCH;

  int frow = lane & 15;
  int g4 = lane >> 4;     // chunk group 0..3
  int fk8 = g4 * 8;

  // B staging: threads 0-127 hi plane, 128-255 lo plane; thread stages col sc's 32 k.
  int sp = tid >> 7;
  int sc = tid & 127;
  const ushort* wsrc = (sp ? WtL : WtH) + (size_t)sc * 1152;
  ushort* Bss = (sp ? BsL : BsH) + sc * 32;
  int sx = sc & 3;  // XOR key for chunk placement

  f32x4 acc[4][4];
  #pragma unroll
  for (int i = 0; i < 4; i++)
    #pragma unroll
    for (int j = 0; j < 4; j++) acc[i][j] = (f32x4){0.f, 0.f, 0.f, 0.f};

  uint4 praw[2][4][2];  // [buf][ft][plane/half]
  uint4 rb[4];
  short8 aH[4], aL[4];

  int arow[4];
  #pragma unroll
  for (int ft = 0; ft < 4; ft++) {
    int r = n0 + wr * 64 + ft * 16 + frow;
    arow[ft] = (r < N) ? r : (N - 1);  // clamp: OOB rows compute garbage, never stored
  }

  #define LOADA(kc, buf)                                                         \
    {                                                                            \
      if ((kc) < 32) {                                                           \
        _Pragma("unroll")                                                        \
        for (int ft = 0; ft < 4; ft++) {                                         \
          const ushort* p_ = aggP + (size_t)arow[ft] * 2048 + (kc) * 64 + fk8;   \
          praw[buf][ft][0] = *(const uint4*)(p_);                                \
          praw[buf][ft][1] = *(const uint4*)(p_ + 32);                           \
        }                                                                        \
      } else {                                                                   \
        _Pragma("unroll")                                                        \
        for (int ft = 0; ft < 4; ft++) {                                         \
          const uint4* xp = (const uint4*)(xf + (size_t)arow[ft] * 128 +         \
                                           ((kc) - 32) * 32 + fk8);              \
          praw[buf][ft][0] = xp[0];                                              \
          praw[buf][ft][1] = xp[1];                                              \
        }                                                                        \
      }                                                                          \
    }
  #define LOADB(kc)                                                              \
    {                                                                            \
      const uint4* ws_ = (const uint4*)(wsrc + (kc) * 32);                       \
      rb[0] = ws_[0]; rb[1] = ws_[1]; rb[2] = ws_[2]; rb[3] = ws_[3];            \
    }

  LOADA(k0, 0);
  LOADA(k0 + 1, 1);
  LOADB(k0);

  for (int kc = k0; kc < kend; kc++) {
    int cur = (kc - k0) & 1;
    // stage B with XOR-chunk placement: chunk i -> offset ((i^sx)*8)
    *(uint4*)(Bss + ((0 ^ sx) << 3)) = rb[0];
    *(uint4*)(Bss + ((1 ^ sx) << 3)) = rb[1];
    *(uint4*)(Bss + ((2 ^ sx) << 3)) = rb[2];
    *(uint4*)(Bss + ((3 ^ sx) << 3)) = rb[3];
    __syncthreads();

    // decode current A frags
    if (kc < 32) {
      #pragma unroll
      for (int ft = 0; ft < 4; ft++) {
        U128 uh, ul;
        uh.u = praw[cur][ft][0];
        ul.u = praw[cur][ft][1];
        aH[ft] = uh.s;
        aL[ft] = ul.s;
      }
    } else {
      #pragma unroll
      for (int ft = 0; ft < 4; ft++) {
        union { uint4 u[2]; float f[8]; } xx;
        xx.u[0] = praw[cur][ft][0];
        xx.u[1] = praw[cur][ft][1];
        short8 th, tl;
        #pragma unroll
        for (int j = 0; j < 8; j++) {
          ushort hb = f2bf(xx.f[j]);
          th[j] = (short)hb;
          tl[j] = (short)f2bf(xx.f[j] - bf2f(hb));
        }
        aH[ft] = th;
        aL[ft] = tl;
      }
    }

    if (kc + 2 < kend) LOADA(kc + 2, cur);
    if (kc + 1 < kend) LOADB(kc + 1);

    #pragma unroll
    for (int ct = 0; ct < 4; ct++) {
      int gcol = wc * 64 + ct * 16 + frow;
      int boff = gcol * 32 + ((g4 ^ (frow & 3)) << 3);  // matches staging XOR
      const short8 bH = *(const short8*)(BsH + boff);
      const short8 bL = *(const short8*)(BsL + boff);
      #pragma unroll
      for (int ft = 0; ft < 4; ft++) {
        acc[ft][ct] = __builtin_amdgcn_mfma_f32_16x16x32_bf16(aH[ft], bH, acc[ft][ct], 0, 0, 0);
        acc[ft][ct] = __builtin_amdgcn_mfma_f32_16x16x32_bf16(aH[ft], bL, acc[ft][ct], 0, 0, 0);
        acc[ft][ct] = __builtin_amdgcn_mfma_f32_16x16x32_bf16(aL[ft], bH, acc[ft][ct], 0, 0, 0);
      }
    }
    __syncthreads();
  }
  #undef LOADA
  #undef LOADB

  // epilogue: raw partial sums; D layout col=lane&15, row=(lane>>4)*4+q
  float* po = part + (size_t)blockIdx.y * N * DH;
  int rbase = n0 + wr * 64 + (lane >> 4) * 4;
  #pragma unroll
  for (int ft = 0; ft < 4; ft++) {
    #pragma unroll
    for (int ct = 0; ct < 4; ct++) {
      int C = wc * 64 + ct * 16 + frow;
      #pragma unroll
      for (int q = 0; q < 4; q++) {
        int R = rbase + ft * 16 + q;
        if (R < N) po[(size_t)R * DH + C] = acc[ft][ct][q];
      }
    }
  }
}

// ---------- layer-2 transform (fused split-K combine + bias + relu) ----------
__global__ __launch_bounds__(256) void k_l2trans(const float* __restrict__ part, const float* __restrict__ b1,
                                                 const float* __restrict__ W2, const float* __restrict__ Wr2,
                                                 float* __restrict__ t, int N) {
  __shared__ float Wt[18 * 128];
  int tid = threadIdx.x;
  for (int i = tid; i < 2304; i += 256) {
    float v; int oc, d;
    if (i < 2048) { int r = i >> 8, rem = i & 255; d = rem >> 1; int c = rem & 1; oc = r * 2 + c; v = W2[i]; }
    else { int i2 = i - 2048; d = i2 >> 1; int c = i2 & 1; oc = 16 + c; v = Wr2[i2]; }
    Wt[oc * 128 + d] = v;
  }
  __syncthreads();
  int node = blockIdx.x * 4 + (tid >> 6);
  int lane = tid & 63;
  if (node >= N) return;
  size_t NP = (size_t)N * DH;
  float2 a0 = *(const float2*)(part + (size_t)node * DH + lane * 2);
  float2 a1 = *(const float2*)(part + NP + (size_t)node * DH + lane * 2);
  float2 bb = *(const float2*)(b1 + lane * 2);
  float2 hv;
  hv.x = fmaxf(a0.x + a1.x + bb.x, 0.f);
  hv.y = fmaxf(a0.y + a1.y + bb.y, 0.f);
  #pragma unroll
  for (int oc = 0; oc < 18; oc++) {
    float2 w = *(const float2*)(Wt + oc * 128 + lane * 2);
    float p = hv.x * w.x + hv.y * w.y;
    p += __shfl_xor(p, 32); p += __shfl_xor(p, 16); p += __shfl_xor(p, 8);
    p += __shfl_xor(p, 4);  p += __shfl_xor(p, 2);  p += __shfl_xor(p, 1);
    if (lane == 0) t[(size_t)node * 18 + oc] = p;
  }
}

// ---------- output: gather tiny t values per segment ----------
__global__ __launch_bounds__(256) void k_out2(const int* __restrict__ offs, const int* __restrict__ hist,
                                              const int* __restrict__ sorted_src, const float* __restrict__ t,
                                              const float* __restrict__ b2, float* __restrict__ out, int N) {
  int n = blockIdx.x * 256 + threadIdx.x;
  if (n >= N) return;
  float o0 = t[(size_t)n * 18 + 16] + b2[0];
  float o1 = t[(size_t)n * 18 + 17] + b2[1];
  #pragma unroll
  for (int r = 0; r < NR; r++) {
    int seg = n * NR + r;
    int en = offs[seg], cc = hist[seg];
    float s0 = 0.f, s1 = 0.f;
    for (int i = en - cc; i < en; i++) {
      int s = sorted_src[i];
      s0 += t[(size_t)s * 18 + r * 2];
      s1 += t[(size_t)s * 18 + r * 2 + 1];
    }
    float inv = 1.f / fmaxf((float)cc, 1.f);
    o0 += s0 * inv;
    o1 += s1 * inv;
  }
  out[(size_t)n * 2 + 0] = o0;
  out[(size_t)n * 2 + 1] = o1;
}

extern "C" void kernel_launch(void* const* d_in, const int* in_sizes, int n_in,
                              void* d_out, int out_size, void* d_ws, size_t ws_size,
                              hipStream_t stream) {
  const float* x   = (const float*)d_in[0];
  const int*   ei  = (const int*)d_in[1];
  const int*   et  = (const int*)d_in[2];
  const float* W1  = (const float*)d_in[3];
  const float* Wr1 = (const float*)d_in[4];
  const float* b1  = (const float*)d_in[5];
  const float* W2  = (const float*)d_in[6];
  const float* Wr2 = (const float*)d_in[7];
  const float* b2  = (const float*)d_in[8];
  float* out = (float*)d_out;

  int E = in_sizes[1] / 2;
  int N = in_sizes[0] / DH;
  int S = N * NR;
  const int* src = ei;
  const int* dst = ei + E;

  // ws layout: ints | aggP (packed hi/lo) | WtH WtL | part(2*N*128 f32) | t
  int* hist       = (int*)d_ws;                  // S
  int* offs       = hist + S;                    // S
  int* blksum     = offs + S;                    // 1024
  int* blkoff     = blksum + 1024;               // 1024
  int* sorted_src = blkoff + 1024;               // E
  size_t int_elems = (size_t)S * 2 + 2048 + E;
  int_elems = (int_elems + 3) & ~(size_t)3;      // 16B align
  ushort* aggP = (ushort*)(hist + int_elems);    // S*256
  ushort* WtH  = aggP + (size_t)S * 256;         // 128*1152
  ushort* WtL  = WtH + 128 * 1152;               // 128*1152
  size_t ush_elems = (size_t)S * 256 + 2 * 128 * 1152;
  float* part = (float*)(aggP + ush_elems);      // 2*N*128
  float* t    = part + (size_t)2 * N * DH;       // N*18

  hipMemsetAsync(hist, 0, sizeof(int) * (size_t)S, stream);

  k_hist<<<(E + 255) / 256, 256, 0, stream>>>(dst, et, hist, E);

  int NB = (S + 1023) / 1024;
  k_scan_local<<<NB, 256, 0, stream>>>(hist, offs, blksum, S);
  k_scan_blk<<<1, 512, 0, stream>>>(blksum, blkoff, NB);
  k_scan_add<<<NB, 256, 0, stream>>>(offs, blkoff, S);

  k_scatter_idx<<<(E + 255) / 256, 256, 0, stream>>>(src, dst, et, offs, sorted_src, E);

  k_wsplit<<<dim3(128, 9), 128, 0, stream>>>(W1, Wr1, WtH, WtL);

  k_agg1<<<(S + 3) / 4, 256, 0, stream>>>(offs, hist, sorted_src, x, aggP, S);

  k_gemm1_mfma<<<dim3((N + 127) / 128, 2), 256, 0, stream>>>(aggP, x, WtH, WtL, part, N);

  k_l2trans<<<(N + 3) / 4, 256, 0, stream>>>(part, b1, W2, Wr2, t, N);

  k_out2<<<(N + 255) / 256, 256, 0, stream>>>(offs, hist, sorted_src, t, b2, out, N);
}

// Round 10
// 487.827 us; speedup vs baseline: 1.5445x; 1.3949x over previous
//
#include <hip/hip_runtime.h>
#include <hip/hip_bf16.h>

// RGCN 2-layer forward, f32 accuracy. CSR counting-sort; layer-1 GEMM via
// split-bf16 (hi+lo) 3-term MFMA, split-K=2, BM=128, packed hi/lo A layout,
// STATIC 2-deep A prefetch (named praw0/praw1, loop unrolled by 2 — rule #20).
// L1: aggP[node][8rel*4ch][2pl][32] = bf16-split mean x[src];
//     part[kq] = [agg|x]_kq @ [W1;Wr1]_kq  (MFMA, 782 blocks)
// L2: hv = relu(part0+part1+b1) folded into t[n,0:18] = hv @ [W2_r(:,0:2).. | Wr2];
//     out = sum_r mean t[src,2r:2r+2] + t[n,16:18] + b2.

#define NR 8
#define DH 128
#define KCH 18  // kc chunks (32-wide) per split-K block; 36 total; must be even

typedef short short8 __attribute__((ext_vector_type(8)));
typedef float f32x4 __attribute__((ext_vector_type(4)));

__device__ inline ushort f2bf(float v) {
  __hip_bfloat16 b = __float2bfloat16(v);
  return *reinterpret_cast<ushort*>(&b);
}
__device__ inline float bf2f(ushort u) {
  __hip_bfloat16 b;
  *reinterpret_cast<ushort*>(&b) = u;
  return __bfloat162float(b);
}
union U128 { uint4 u; short8 s; };

// ---------- counting sort ----------
__global__ __launch_bounds__(256) void k_hist(const int* __restrict__ dst, const int* __restrict__ et,
                                              int* __restrict__ hist, int E) {
  int e = blockIdx.x * 256 + threadIdx.x;
  if (e < E) atomicAdd(&hist[dst[e] * NR + et[e]], 1);
}

__global__ __launch_bounds__(256) void k_scan_local(const int* __restrict__ hist, int* __restrict__ offs,
                                                    int* __restrict__ blksum, int S) {
  __shared__ int tsum[256];
  int tid = threadIdx.x;
  int base = blockIdx.x * 1024 + tid * 4;
  int v[4], tot = 0;
  #pragma unroll
  for (int i = 0; i < 4; i++) { v[i] = (base + i < S) ? hist[base + i] : 0; tot += v[i]; }
  tsum[tid] = tot;
  __syncthreads();
  for (int off = 1; off < 256; off <<= 1) {
    int val = tsum[tid];
    int add = (tid >= off) ? tsum[tid - off] : 0;
    __syncthreads();
    tsum[tid] = val + add;
    __syncthreads();
  }
  int run = tsum[tid] - tot;
  #pragma unroll
  for (int i = 0; i < 4; i++) {
    if (base + i < S) offs[base + i] = run;
    run += v[i];
  }
  if (tid == 255) blksum[blockIdx.x] = tsum[255];
}

__global__ __launch_bounds__(512) void k_scan_blk(const int* __restrict__ blksum, int* __restrict__ blkoff, int NB) {
  __shared__ int s[512];
  int tid = threadIdx.x;
  int v = (tid < NB) ? blksum[tid] : 0;
  s[tid] = v;
  __syncthreads();
  for (int off = 1; off < 512; off <<= 1) {
    int val = s[tid];
    int add = (tid >= off) ? s[tid - off] : 0;
    __syncthreads();
    s[tid] = val + add;
    __syncthreads();
  }
  if (tid < NB) blkoff[tid] = s[tid] - v;
}

__global__ __launch_bounds__(256) void k_scan_add(int* __restrict__ offs, const int* __restrict__ blkoff, int S) {
  int tid = threadIdx.x;
  int base = blockIdx.x * 1024 + tid * 4;
  int add = blkoff[blockIdx.x];
  #pragma unroll
  for (int i = 0; i < 4; i++)
    if (base + i < S) offs[base + i] += add;
}

__global__ __launch_bounds__(256) void k_scatter_idx(const int* __restrict__ src, const int* __restrict__ dst,
                                                     const int* __restrict__ et, int* __restrict__ offs,
                                                     int* __restrict__ sorted_src, int E) {
  int e = blockIdx.x * 256 + threadIdx.x;
  if (e >= E) return;
  int seg = dst[e] * NR + et[e];
  int pos = atomicAdd(&offs[seg], 1);
  sorted_src[pos] = src[e];
}

// ---------- W split+transpose: Wt[col][k], k in [0,1152) ----------
__global__ __launch_bounds__(128) void k_wsplit(const float* __restrict__ W1, const float* __restrict__ Wr1,
                                                ushort* __restrict__ WtH, ushort* __restrict__ WtL) {
  int c = blockIdx.x;
  int k = blockIdx.y * 128 + threadIdx.x;
  float v = (k < 1024) ? W1[(size_t)k * 128 + c] : Wr1[(size_t)(k - 1024) * 128 + c];
  ushort hi = f2bf(v);
  ushort lo = f2bf(v - bf2f(hi));
  WtH[(size_t)c * 1152 + k] = hi;
  WtL[(size_t)c * 1152 + k] = lo;
}

// ---------- layer 1 aggregate: packed hi/lo per 32-chunk: aggP[seg][c][plane][32] ----------
__global__ __launch_bounds__(256) void k_agg1(const int* __restrict__ offs, const int* __restrict__ hist,
                                              const int* __restrict__ sorted_src, const float* __restrict__ x,
                                              ushort* __restrict__ aggP, int S) {
  int tid = threadIdx.x;
  int seg = blockIdx.x * 4 + (tid >> 6);
  int lane = tid & 63;
  if (seg >= S) return;
  int end = offs[seg];
  int cnt = hist[seg];
  int st = end - cnt;
  float ax = 0.f, ay = 0.f;
  int i = st;
  for (; i + 4 <= end; i += 4) {
    int s0 = sorted_src[i + 0];
    int s1 = sorted_src[i + 1];
    int s2 = sorted_src[i + 2];
    int s3 = sorted_src[i + 3];
    float2 v0 = *(const float2*)(x + (size_t)s0 * DH + lane * 2);
    float2 v1 = *(const float2*)(x + (size_t)s1 * DH + lane * 2);
    float2 v2 = *(const float2*)(x + (size_t)s2 * DH + lane * 2);
    float2 v3 = *(const float2*)(x + (size_t)s3 * DH + lane * 2);
    ax += (v0.x + v1.x) + (v2.x + v3.x);
    ay += (v0.y + v1.y) + (v2.y + v3.y);
  }
  for (; i < end; i++) {
    int s = sorted_src[i];
    float2 v = *(const float2*)(x + (size_t)s * DH + lane * 2);
    ax += v.x;
    ay += v.y;
  }
  float inv = 1.f / fmaxf((float)cnt, 1.f);
  ax *= inv;
  ay *= inv;
  ushort hx = f2bf(ax), hy = f2bf(ay);
  ushort lx = f2bf(ax - bf2f(hx)), ly = f2bf(ay - bf2f(hy));
  ushort2 hv; hv.x = hx; hv.y = hy;
  ushort2 lv; lv.x = lx; lv.y = ly;
  // lane covers k = {lane*2, lane*2+1}: chunk = lane>>4, pos = (lane*2)&31
  ushort* base = aggP + (size_t)seg * 256 + (lane >> 4) * 64 + ((lane * 2) & 31);
  *(ushort2*)(base) = hv;
  *(ushort2*)(base + 32) = lv;
}

// ---------- layer 1 MFMA GEMM, split-K=2, BM=128, static 2-deep A prefetch ----------
// 256 thr = 4 waves (2 wr x 2 wc), block tile 128x128, wave tile 64x64 (4x4 frags).
// A-frags direct from global (hi+lo share one 128B line, packed layout).
// B staged in LDS with XOR-chunk swizzle. part[kq][n][c] = partial sums.
__global__ __launch_bounds__(256) void k_gemm1_mfma(
    const ushort* __restrict__ aggP, const float* __restrict__ xf,
    const ushort* __restrict__ WtH, const ushort* __restrict__ WtL,
    float* __restrict__ part, int N) {
  __shared__ ushort BsH[128 * 32];
  __shared__ ushort BsL[128 * 32];

  int tid = threadIdx.x;
  int w = tid >> 6, lane = tid & 63;
  int wr = w >> 1, wc = w & 1;
  int n0 = blockIdx.x * 128;
  int k0 = blockIdx.y * KCH;
  int kend = k0 + KCH;

  int frow = lane & 15;
  int g4 = lane >> 4;     // chunk group 0..3
  int fk8 = g4 * 8;

  // B staging: threads 0-127 hi plane, 128-255 lo plane; thread stages col sc's 32 k.
  int sp = tid >> 7;
  int sc = tid & 127;
  const ushort* wsrc = (sp ? WtL : WtH) + (size_t)sc * 1152;
  ushort* Bss = (sp ? BsL : BsH) + sc * 32;
  int sx = sc & 3;  // XOR key for chunk placement

  f32x4 acc[4][4];
  #pragma unroll
  for (int i = 0; i < 4; i++)
    #pragma unroll
    for (int j = 0; j < 4; j++) acc[i][j] = (f32x4){0.f, 0.f, 0.f, 0.f};

  uint4 praw0[4][2], praw1[4][2];  // static names only — rule #20 (no runtime idx)
  uint4 rb[4];
  short8 aH[4], aL[4];

  int arow[4];
  #pragma unroll
  for (int ft = 0; ft < 4; ft++) {
    int r = n0 + wr * 64 + ft * 16 + frow;
    arow[ft] = (r < N) ? r : (N - 1);  // clamp: OOB rows compute garbage, never stored
  }

  #define LOADA(kc, P)                                                           \
    {                                                                            \
      if ((kc) < 32) {                                                           \
        _Pragma("unroll")                                                        \
        for (int ft = 0; ft < 4; ft++) {                                         \
          const ushort* p_ = aggP + (size_t)arow[ft] * 2048 + (kc) * 64 + fk8;   \
          P[ft][0] = *(const uint4*)(p_);                                        \
          P[ft][1] = *(const uint4*)(p_ + 32);                                   \
        }                                                                        \
      } else {                                                                   \
        _Pragma("unroll")                                                        \
        for (int ft = 0; ft < 4; ft++) {                                         \
          const uint4* xp = (const uint4*)(xf + (size_t)arow[ft] * 128 +         \
                                           ((kc) - 32) * 32 + fk8);              \
          P[ft][0] = xp[0];                                                      \
          P[ft][1] = xp[1];                                                      \
        }                                                                        \
      }                                                                          \
    }
  #define LOADB(kc)                                                              \
    {                                                                            \
      const uint4* ws_ = (const uint4*)(wsrc + (kc) * 32);                       \
      rb[0] = ws_[0]; rb[1] = ws_[1]; rb[2] = ws_[2]; rb[3] = ws_[3];            \
    }
  #define STAGEB()                                                               \
    {                                                                            \
      *(uint4*)(Bss + ((0 ^ sx) << 3)) = rb[0];                                  \
      *(uint4*)(Bss + ((1 ^ sx) << 3)) = rb[1];                                  \
      *(uint4*)(Bss + ((2 ^ sx) << 3)) = rb[2];                                  \
      *(uint4*)(Bss + ((3 ^ sx) << 3)) = rb[3];                                  \
    }
  #define DECODE(kc, P)                                                          \
    {                                                                            \
      if ((kc) < 32) {                                                           \
        _Pragma("unroll")                                                        \
        for (int ft = 0; ft < 4; ft++) {                                         \
          U128 uh_, ul_;                                                         \
          uh_.u = P[ft][0];                                                      \
          ul_.u = P[ft][1];                                                      \
          aH[ft] = uh_.s;                                                        \
          aL[ft] = ul_.s;                                                        \
        }                                                                        \
      } else {                                                                   \
        _Pragma("unroll")                                                        \
        for (int ft = 0; ft < 4; ft++) {                                         \
          union { uint4 u[2]; float f[8]; } xx_;                                 \
          xx_.u[0] = P[ft][0];                                                   \
          xx_.u[1] = P[ft][1];                                                   \
          short8 th_, tl_;                                                       \
          _Pragma("unroll")                                                      \
          for (int j = 0; j < 8; j++) {                                          \
            ushort hb_ = f2bf(xx_.f[j]);                                         \
            th_[j] = (short)hb_;                                                 \
            tl_[j] = (short)f2bf(xx_.f[j] - bf2f(hb_));                          \
          }                                                                      \
          aH[ft] = th_;                                                          \
          aL[ft] = tl_;                                                          \
        }                                                                        \
      }                                                                          \
    }
  #define MFMAS()                                                                \
    {                                                                            \
      _Pragma("unroll")                                                          \
      for (int ct = 0; ct < 4; ct++) {                                           \
        int gcol = wc * 64 + ct * 16 + frow;                                     \
        int boff = gcol * 32 + ((g4 ^ (frow & 3)) << 3);                         \
        const short8 bH = *(const short8*)(BsH + boff);                          \
        const short8 bL = *(const short8*)(BsL + boff);                          \
        _Pragma("unroll")                                                        \
        for (int ft = 0; ft < 4; ft++) {                                         \
          acc[ft][ct] = __builtin_amdgcn_mfma_f32_16x16x32_bf16(aH[ft], bH, acc[ft][ct], 0, 0, 0); \
          acc[ft][ct] = __builtin_amdgcn_mfma_f32_16x16x32_bf16(aH[ft], bL, acc[ft][ct], 0, 0, 0); \
          acc[ft][ct] = __builtin_amdgcn_mfma_f32_16x16x32_bf16(aL[ft], bH, acc[ft][ct], 0, 0, 0); \
        }                                                                        \
      }                                                                          \
    }

  LOADA(k0, praw0);
  LOADA(k0 + 1, praw1);
  LOADB(k0);

  for (int kc = k0; kc < kend; kc += 2) {
    // phase 0: compute kc (praw0)
    STAGEB();
    __syncthreads();
    DECODE(kc, praw0);
    if (kc + 2 < kend) LOADA(kc + 2, praw0);
    LOADB(kc + 1);
    MFMAS();
    __syncthreads();

    // phase 1: compute kc+1 (praw1)
    STAGEB();
    __syncthreads();
    DECODE(kc + 1, praw1);
    if (kc + 3 < kend) LOADA(kc + 3, praw1);
    if (kc + 2 < kend) LOADB(kc + 2);
    MFMAS();
    __syncthreads();
  }
  #undef LOADA
  #undef LOADB
  #undef STAGEB
  #undef DECODE
  #undef MFMAS

  // epilogue: raw partial sums; D layout col=lane&15, row=(lane>>4)*4+q
  float* po = part + (size_t)blockIdx.y * N * DH;
  int rbase = n0 + wr * 64 + (lane >> 4) * 4;
  #pragma unroll
  for (int ft = 0; ft < 4; ft++) {
    #pragma unroll
    for (int ct = 0; ct < 4; ct++) {
      int C = wc * 64 + ct * 16 + frow;
      #pragma unroll
      for (int q = 0; q < 4; q++) {
        int R = rbase + ft * 16 + q;
        if (R < N) po[(size_t)R * DH + C] = acc[ft][ct][q];
      }
    }
  }
}

// ---------- layer-2 transform (fused split-K combine + bias + relu) ----------
__global__ __launch_bounds__(256) void k_l2trans(const float* __restrict__ part, const float* __restrict__ b1,
                                                 const float* __restrict__ W2, const float* __restrict__ Wr2,
                                                 float* __restrict__ t, int N) {
  __shared__ float Wt[18 * 128];
  int tid = threadIdx.x;
  for (int i = tid; i < 2304; i += 256) {
    float v; int oc, d;
    if (i < 2048) { int r = i >> 8, rem = i & 255; d = rem >> 1; int c = rem & 1; oc = r * 2 + c; v = W2[i]; }
    else { int i2 = i - 2048; d = i2 >> 1; int c = i2 & 1; oc = 16 + c; v = Wr2[i2]; }
    Wt[oc * 128 + d] = v;
  }
  __syncthreads();
  int node = blockIdx.x * 4 + (tid >> 6);
  int lane = tid & 63;
  if (node >= N) return;
  size_t NP = (size_t)N * DH;
  float2 a0 = *(const float2*)(part + (size_t)node * DH + lane * 2);
  float2 a1 = *(const float2*)(part + NP + (size_t)node * DH + lane * 2);
  float2 bb = *(const float2*)(b1 + lane * 2);
  float2 hv;
  hv.x = fmaxf(a0.x + a1.x + bb.x, 0.f);
  hv.y = fmaxf(a0.y + a1.y + bb.y, 0.f);
  #pragma unroll
  for (int oc = 0; oc < 18; oc++) {
    float2 w = *(const float2*)(Wt + oc * 128 + lane * 2);
    float p = hv.x * w.x + hv.y * w.y;
    p += __shfl_xor(p, 32); p += __shfl_xor(p, 16); p += __shfl_xor(p, 8);
    p += __shfl_xor(p, 4);  p += __shfl_xor(p, 2);  p += __shfl_xor(p, 1);
    if (lane == 0) t[(size_t)node * 18 + oc] = p;
  }
}

// ---------- output: gather tiny t values per segment ----------
__global__ __launch_bounds__(256) void k_out2(const int* __restrict__ offs, const int* __restrict__ hist,
                                              const int* __restrict__ sorted_src, const float* __restrict__ t,
                                              const float* __restrict__ b2, float* __restrict__ out, int N) {
  int n = blockIdx.x * 256 + threadIdx.x;
  if (n >= N) return;
  float o0 = t[(size_t)n * 18 + 16] + b2[0];
  float o1 = t[(size_t)n * 18 + 17] + b2[1];
  #pragma unroll
  for (int r = 0; r < NR; r++) {
    int seg = n * NR + r;
    int en = offs[seg], cc = hist[seg];
    float s0 = 0.f, s1 = 0.f;
    for (int i = en - cc; i < en; i++) {
      int s = sorted_src[i];
      s0 += t[(size_t)s * 18 + r * 2];
      s1 += t[(size_t)s * 18 + r * 2 + 1];
    }
    float inv = 1.f / fmaxf((float)cc, 1.f);
    o0 += s0 * inv;
    o1 += s1 * inv;
  }
  out[(size_t)n * 2 + 0] = o0;
  out[(size_t)n * 2 + 1] = o1;
}

extern "C" void kernel_launch(void* const* d_in, const int* in_sizes, int n_in,
                              void* d_out, int out_size, void* d_ws, size_t ws_size,
                              hipStream_t stream) {
  const float* x   = (const float*)d_in[0];
  const int*   ei  = (const int*)d_in[1];
  const int*   et  = (const int*)d_in[2];
  const float* W1  = (const float*)d_in[3];
  const float* Wr1 = (const float*)d_in[4];
  const float* b1  = (const float*)d_in[5];
  const float* W2  = (const float*)d_in[6];
  const float* Wr2 = (const float*)d_in[7];
  const float* b2  = (const float*)d_in[8];
  float* out = (float*)d_out;

  int E = in_sizes[1] / 2;
  int N = in_sizes[0] / DH;
  int S = N * NR;
  const int* src = ei;
  const int* dst = ei + E;

  // ws layout: ints | aggP (packed hi/lo) | WtH WtL | part(2*N*128 f32) | t
  int* hist       = (int*)d_ws;                  // S
  int* offs       = hist + S;                    // S
  int* blksum     = offs + S;                    // 1024
  int* blkoff     = blksum + 1024;               // 1024
  int* sorted_src = blkoff + 1024;               // E
  size_t int_elems = (size_t)S * 2 + 2048 + E;
  int_elems = (int_elems + 3) & ~(size_t)3;      // 16B align
  ushort* aggP = (ushort*)(hist + int_elems);    // S*256
  ushort* WtH  = aggP + (size_t)S * 256;         // 128*1152
  ushort* WtL  = WtH + 128 * 1152;               // 128*1152
  size_t ush_elems = (size_t)S * 256 + 2 * 128 * 1152;
  float* part = (float*)(aggP + ush_elems);      // 2*N*128
  float* t    = part + (size_t)2 * N * DH;       // N*18

  hipMemsetAsync(hist, 0, sizeof(int) * (size_t)S, stream);

  k_hist<<<(E + 255) / 256, 256, 0, stream>>>(dst, et, hist, E);

  int NB = (S + 1023) / 1024;
  k_scan_local<<<NB, 256, 0, stream>>>(hist, offs, blksum, S);
  k_scan_blk<<<1, 512, 0, stream>>>(blksum, blkoff, NB);
  k_scan_add<<<NB, 256, 0, stream>>>(offs, blkoff, S);

  k_scatter_idx<<<(E + 255) / 256, 256, 0, stream>>>(src, dst, et, offs, sorted_src, E);

  k_wsplit<<<dim3(128, 9), 128, 0, stream>>>(W1, Wr1, WtH, WtL);

  k_agg1<<<(S + 3) / 4, 256, 0, stream>>>(offs, hist, sorted_src, x, aggP, S);

  k_gemm1_mfma<<<dim3((N + 127) / 128, 2), 256, 0, stream>>>(aggP, x, WtH, WtL, part, N);

  k_l2trans<<<(N + 3) / 4, 256, 0, stream>>>(part, b1, W2, Wr2, t, N);

  k_out2<<<(N + 255) / 256, 256, 0, stream>>>(offs, hist, sorted_src, t, b2, out, N);
}

// Round 11
// 482.702 us; speedup vs baseline: 1.5609x; 1.0106x over previous
//
#include <hip/hip_runtime.h>
#include <hip/hip_bf16.h>

// RGCN 2-layer forward, f32 accuracy. CSR counting-sort; layer-1 GEMM via
// split-bf16 (hi+lo) 3-term MFMA. BARRIER-FREE GEMM: no LDS, B register-direct
// from L2-resident Wt (col-major), A 3-buf / B 2-buf static prefetch, all 18
// phases unrolled (rule #20: every buffer index compile-time).
// L1: aggP[seg][4ch][2pl][32] = bf16-split mean x[src];
//     part[kq] = [agg|x]_kq @ [W1;Wr1]_kq  (split-K=2, BM=64, 1564 blocks)
// L2: hv = relu(part0+part1+b1) folded into t[n,0:18] = hv @ [W2_r(:,0:2).. | Wr2];
//     out = sum_r mean t[src,2r:2r+2] + t[n,16:18] + b2.

#define NR 8
#define DH 128
#define KCH 18  // kc chunks (32-wide) per split-K block; 36 total

typedef short short8 __attribute__((ext_vector_type(8)));
typedef float f32x4 __attribute__((ext_vector_type(4)));

__device__ inline ushort f2bf(float v) {
  __hip_bfloat16 b = __float2bfloat16(v);
  return *reinterpret_cast<ushort*>(&b);
}
__device__ inline float bf2f(ushort u) {
  __hip_bfloat16 b;
  *reinterpret_cast<ushort*>(&b) = u;
  return __bfloat162float(b);
}
union U128 { uint4 u; short8 s; };

// ---------- counting sort ----------
__global__ __launch_bounds__(256) void k_hist(const int* __restrict__ dst, const int* __restrict__ et,
                                              int* __restrict__ hist, int E) {
  int e = blockIdx.x * 256 + threadIdx.x;
  if (e < E) atomicAdd(&hist[dst[e] * NR + et[e]], 1);
}

__global__ __launch_bounds__(256) void k_scan_local(const int* __restrict__ hist, int* __restrict__ offs,
                                                    int* __restrict__ blksum, int S) {
  __shared__ int tsum[256];
  int tid = threadIdx.x;
  int base = blockIdx.x * 1024 + tid * 4;
  int v[4], tot = 0;
  #pragma unroll
  for (int i = 0; i < 4; i++) { v[i] = (base + i < S) ? hist[base + i] : 0; tot += v[i]; }
  tsum[tid] = tot;
  __syncthreads();
  for (int off = 1; off < 256; off <<= 1) {
    int val = tsum[tid];
    int add = (tid >= off) ? tsum[tid - off] : 0;
    __syncthreads();
    tsum[tid] = val + add;
    __syncthreads();
  }
  int run = tsum[tid] - tot;
  #pragma unroll
  for (int i = 0; i < 4; i++) {
    if (base + i < S) offs[base + i] = run;
    run += v[i];
  }
  if (tid == 255) blksum[blockIdx.x] = tsum[255];
}

__global__ __launch_bounds__(512) void k_scan_blk(const int* __restrict__ blksum, int* __restrict__ blkoff, int NB) {
  __shared__ int s[512];
  int tid = threadIdx.x;
  int v = (tid < NB) ? blksum[tid] : 0;
  s[tid] = v;
  __syncthreads();
  for (int off = 1; off < 512; off <<= 1) {
    int val = s[tid];
    int add = (tid >= off) ? s[tid - off] : 0;
    __syncthreads();
    s[tid] = val + add;
    __syncthreads();
  }
  if (tid < NB) blkoff[tid] = s[tid] - v;
}

__global__ __launch_bounds__(256) void k_scan_add(int* __restrict__ offs, const int* __restrict__ blkoff, int S) {
  int tid = threadIdx.x;
  int base = blockIdx.x * 1024 + tid * 4;
  int add = blkoff[blockIdx.x];
  #pragma unroll
  for (int i = 0; i < 4; i++)
    if (base + i < S) offs[base + i] += add;
}

__global__ __launch_bounds__(256) void k_scatter_idx(const int* __restrict__ src, const int* __restrict__ dst,
                                                     const int* __restrict__ et, int* __restrict__ offs,
                                                     int* __restrict__ sorted_src, int E) {
  int e = blockIdx.x * 256 + threadIdx.x;
  if (e >= E) return;
  int seg = dst[e] * NR + et[e];
  int pos = atomicAdd(&offs[seg], 1);
  sorted_src[pos] = src[e];
}

// ---------- W split+transpose: Wt[col][k], k in [0,1152) ----------
__global__ __launch_bounds__(128) void k_wsplit(const float* __restrict__ W1, const float* __restrict__ Wr1,
                                                ushort* __restrict__ WtH, ushort* __restrict__ WtL) {
  int c = blockIdx.x;
  int k = blockIdx.y * 128 + threadIdx.x;
  float v = (k < 1024) ? W1[(size_t)k * 128 + c] : Wr1[(size_t)(k - 1024) * 128 + c];
  ushort hi = f2bf(v);
  ushort lo = f2bf(v - bf2f(hi));
  WtH[(size_t)c * 1152 + k] = hi;
  WtL[(size_t)c * 1152 + k] = lo;
}

// ---------- layer 1 aggregate: packed hi/lo per 32-chunk: aggP[seg][c][plane][32] ----------
__global__ __launch_bounds__(256) void k_agg1(const int* __restrict__ offs, const int* __restrict__ hist,
                                              const int* __restrict__ sorted_src, const float* __restrict__ x,
                                              ushort* __restrict__ aggP, int S) {
  int tid = threadIdx.x;
  int seg = blockIdx.x * 4 + (tid >> 6);
  int lane = tid & 63;
  if (seg >= S) return;
  int end = offs[seg];
  int cnt = hist[seg];
  int st = end - cnt;
  float ax = 0.f, ay = 0.f;
  int i = st;
  for (; i + 4 <= end; i += 4) {
    int s0 = sorted_src[i + 0];
    int s1 = sorted_src[i + 1];
    int s2 = sorted_src[i + 2];
    int s3 = sorted_src[i + 3];
    float2 v0 = *(const float2*)(x + (size_t)s0 * DH + lane * 2);
    float2 v1 = *(const float2*)(x + (size_t)s1 * DH + lane * 2);
    float2 v2 = *(const float2*)(x + (size_t)s2 * DH + lane * 2);
    float2 v3 = *(const float2*)(x + (size_t)s3 * DH + lane * 2);
    ax += (v0.x + v1.x) + (v2.x + v3.x);
    ay += (v0.y + v1.y) + (v2.y + v3.y);
  }
  for (; i < end; i++) {
    int s = sorted_src[i];
    float2 v = *(const float2*)(x + (size_t)s * DH + lane * 2);
    ax += v.x;
    ay += v.y;
  }
  float inv = 1.f / fmaxf((float)cnt, 1.f);
  ax *= inv;
  ay *= inv;
  ushort hx = f2bf(ax), hy = f2bf(ay);
  ushort lx = f2bf(ax - bf2f(hx)), ly = f2bf(ay - bf2f(hy));
  ushort2 hv; hv.x = hx; hv.y = hy;
  ushort2 lv; lv.x = lx; lv.y = ly;
  // lane covers k = {lane*2, lane*2+1}: chunk = lane>>4, pos = (lane*2)&31
  ushort* base = aggP + (size_t)seg * 256 + (lane >> 4) * 64 + ((lane * 2) & 31);
  *(ushort2*)(base) = hv;
  *(ushort2*)(base + 32) = lv;
}

// ---------- layer 1 MFMA GEMM: barrier-free, no LDS, split-K=2, BM=64 ----------
// 256 thr = 4 waves (2 wr x 2 wc), block tile 64x128, wave tile 32x64 (2x4 frags).
// A: packed aggP (hi/lo in one 128B line), 3-buffer / 2-phase-lead prefetch.
// B: register-direct from col-major WtH/WtL (L2-resident), 2-buffer / 1-phase lead.
// All KCH=18 phases unrolled; every buffer name static (rule #20).
__global__ __launch_bounds__(256) void k_gemm1_mfma(
    const ushort* __restrict__ aggP, const float* __restrict__ xf,
    const ushort* __restrict__ WtH, const ushort* __restrict__ WtL,
    float* __restrict__ part, int N) {
  int tid = threadIdx.x;
  int w = tid >> 6, lane = tid & 63;
  int wr = w >> 1, wc = w & 1;
  int n0 = blockIdx.x * 64;
  int k0 = blockIdx.y * KCH;

  int frow = lane & 15;
  int fk8 = (lane >> 4) * 8;

  f32x4 acc[2][4];
  #pragma unroll
  for (int i = 0; i < 2; i++)
    #pragma unroll
    for (int j = 0; j < 4; j++) acc[i][j] = (f32x4){0.f, 0.f, 0.f, 0.f};

  int arow[2];
  #pragma unroll
  for (int ft = 0; ft < 2; ft++) {
    int r = n0 + wr * 32 + ft * 16 + frow;
    arow[ft] = (r < N) ? r : (N - 1);  // clamp: OOB rows compute garbage, never stored
  }
  int baseB[4];
  #pragma unroll
  for (int ct = 0; ct < 4; ct++) {
    int colW = wc * 64 + ct * 16 + frow;
    baseB[ct] = colW * 1152 + fk8;
  }

  uint4 pa0[2][2], pa1[2][2], pa2[2][2];  // A: [ft][plane-or-half]
  uint4 pb0[4][2], pb1[4][2];             // B: [ct][plane]

  #define LOADA(KC, P)                                                        \
    if ((KC) < 32) {                                                          \
      _Pragma("unroll")                                                       \
      for (int ft = 0; ft < 2; ft++) {                                        \
        const ushort* p_ = aggP + (size_t)arow[ft] * 2048 + (KC) * 64 + fk8;  \
        P[ft][0] = *(const uint4*)(p_);                                       \
        P[ft][1] = *(const uint4*)(p_ + 32);                                  \
      }                                                                       \
    } else {                                                                  \
      _Pragma("unroll")                                                       \
      for (int ft = 0; ft < 2; ft++) {                                        \
        const uint4* xp = (const uint4*)(xf + (size_t)arow[ft] * 128 +        \
                                         ((KC) - 32) * 32 + fk8);             \
        P[ft][0] = xp[0];                                                     \
        P[ft][1] = xp[1];                                                     \
      }                                                                       \
    }

  #define LOADB(KC, P)                                                        \
    {                                                                         \
      _Pragma("unroll")                                                       \
      for (int ct = 0; ct < 4; ct++) {                                        \
        P[ct][0] = *(const uint4*)(WtH + baseB[ct] + (KC) * 32);              \
        P[ct][1] = *(const uint4*)(WtL + baseB[ct] + (KC) * 32);              \
      }                                                                       \
    }

  #define DODECA(KC, P, FT, AH, AL)                                           \
    short8 AH, AL;                                                            \
    if ((KC) < 32) {                                                          \
      U128 uh_, ul_;                                                          \
      uh_.u = P[FT][0]; ul_.u = P[FT][1];                                     \
      AH = uh_.s; AL = ul_.s;                                                 \
    } else {                                                                  \
      union { uint4 u[2]; float f[8]; } xx_;                                  \
      xx_.u[0] = P[FT][0]; xx_.u[1] = P[FT][1];                               \
      _Pragma("unroll")                                                       \
      for (int j = 0; j < 8; j++) {                                           \
        ushort hb_ = f2bf(xx_.f[j]);                                          \
        AH[j] = (short)hb_;                                                   \
        AL[j] = (short)f2bf(xx_.f[j] - bf2f(hb_));                            \
      }                                                                       \
    }

  #define PHASE(I, PAU, PAF, PBU, PBF)                                        \
    {                                                                         \
      if ((I) + 2 < KCH) { LOADA(k0 + (I) + 2, PAF); }                        \
      if ((I) + 1 < KCH) { LOADB(k0 + (I) + 1, PBF); }                        \
      DODECA(k0 + (I), PAU, 0, aH0_, aL0_);                                   \
      DODECA(k0 + (I), PAU, 1, aH1_, aL1_);                                   \
      _Pragma("unroll")                                                       \
      for (int ct = 0; ct < 4; ct++) {                                        \
        U128 bh_, bl_;                                                        \
        bh_.u = PBU[ct][0]; bl_.u = PBU[ct][1];                               \
        const short8 bH = bh_.s;                                              \
        const short8 bL = bl_.s;                                              \
        acc[0][ct] = __builtin_amdgcn_mfma_f32_16x16x32_bf16(aH0_, bH, acc[0][ct], 0, 0, 0); \
        acc[0][ct] = __builtin_amdgcn_mfma_f32_16x16x32_bf16(aH0_, bL, acc[0][ct], 0, 0, 0); \
        acc[0][ct] = __builtin_amdgcn_mfma_f32_16x16x32_bf16(aL0_, bH, acc[0][ct], 0, 0, 0); \
        acc[1][ct] = __builtin_amdgcn_mfma_f32_16x16x32_bf16(aH1_, bH, acc[1][ct], 0, 0, 0); \
        acc[1][ct] = __builtin_amdgcn_mfma_f32_16x16x32_bf16(aH1_, bL, acc[1][ct], 0, 0, 0); \
        acc[1][ct] = __builtin_amdgcn_mfma_f32_16x16x32_bf16(aL1_, bH, acc[1][ct], 0, 0, 0); \
      }                                                                       \
    }

  // prologue: A 2 buffers ahead, B 1 buffer ahead
  LOADA(k0, pa0);
  LOADA(k0 + 1, pa1);
  LOADB(k0, pb0);

  // 18 phases; A: use i%3 / fill (i+2)%3; B: use i%2 / fill (i+1)%2
  PHASE(0,  pa0, pa2, pb0, pb1)
  PHASE(1,  pa1, pa0, pb1, pb0)
  PHASE(2,  pa2, pa1, pb0, pb1)
  PHASE(3,  pa0, pa2, pb1, pb0)
  PHASE(4,  pa1, pa0, pb0, pb1)
  PHASE(5,  pa2, pa1, pb1, pb0)
  PHASE(6,  pa0, pa2, pb0, pb1)
  PHASE(7,  pa1, pa0, pb1, pb0)
  PHASE(8,  pa2, pa1, pb0, pb1)
  PHASE(9,  pa0, pa2, pb1, pb0)
  PHASE(10, pa1, pa0, pb0, pb1)
  PHASE(11, pa2, pa1, pb1, pb0)
  PHASE(12, pa0, pa2, pb0, pb1)
  PHASE(13, pa1, pa0, pb1, pb0)
  PHASE(14, pa2, pa1, pb0, pb1)
  PHASE(15, pa0, pa2, pb1, pb0)
  PHASE(16, pa1, pa0, pb0, pb1)
  PHASE(17, pa2, pa1, pb1, pb0)

  #undef LOADA
  #undef LOADB
  #undef DODECA
  #undef PHASE

  // epilogue: raw partial sums; D layout col=lane&15, row=(lane>>4)*4+q
  float* po = part + (size_t)blockIdx.y * N * DH;
  int rbase = n0 + wr * 32 + (lane >> 4) * 4;
  #pragma unroll
  for (int ft = 0; ft < 2; ft++) {
    #pragma unroll
    for (int ct = 0; ct < 4; ct++) {
      int C = wc * 64 + ct * 16 + frow;
      #pragma unroll
      for (int q = 0; q < 4; q++) {
        int R = rbase + ft * 16 + q;
        if (R < N) po[(size_t)R * DH + C] = acc[ft][ct][q];
      }
    }
  }
}

// ---------- layer-2 transform (fused split-K combine + bias + relu) ----------
__global__ __launch_bounds__(256) void k_l2trans(const float* __restrict__ part, const float* __restrict__ b1,
                                                 const float* __restrict__ W2, const float* __restrict__ Wr2,
                                                 float* __restrict__ t, int N) {
  __shared__ float Wt[18 * 128];
  int tid = threadIdx.x;
  for (int i = tid; i < 2304; i += 256) {
    float v; int oc, d;
    if (i < 2048) { int r = i >> 8, rem = i & 255; d = rem >> 1; int c = rem & 1; oc = r * 2 + c; v = W2[i]; }
    else { int i2 = i - 2048; d = i2 >> 1; int c = i2 & 1; oc = 16 + c; v = Wr2[i2]; }
    Wt[oc * 128 + d] = v;
  }
  __syncthreads();
  int node = blockIdx.x * 4 + (tid >> 6);
  int lane = tid & 63;
  if (node >= N) return;
  size_t NP = (size_t)N * DH;
  float2 a0 = *(const float2*)(part + (size_t)node * DH + lane * 2);
  float2 a1 = *(const float2*)(part + NP + (size_t)node * DH + lane * 2);
  float2 bb = *(const float2*)(b1 + lane * 2);
  float2 hv;
  hv.x = fmaxf(a0.x + a1.x + bb.x, 0.f);
  hv.y = fmaxf(a0.y + a1.y + bb.y, 0.f);
  #pragma unroll
  for (int oc = 0; oc < 18; oc++) {
    float2 w = *(const float2*)(Wt + oc * 128 + lane * 2);
    float p = hv.x * w.x + hv.y * w.y;
    p += __shfl_xor(p, 32); p += __shfl_xor(p, 16); p += __shfl_xor(p, 8);
    p += __shfl_xor(p, 4);  p += __shfl_xor(p, 2);  p += __shfl_xor(p, 1);
    if (lane == 0) t[(size_t)node * 18 + oc] = p;
  }
}

// ---------- output: gather tiny t values per segment ----------
__global__ __launch_bounds__(256) void k_out2(const int* __restrict__ offs, const int* __restrict__ hist,
                                              const int* __restrict__ sorted_src, const float* __restrict__ t,
                                              const float* __restrict__ b2, float* __restrict__ out, int N) {
  int n = blockIdx.x * 256 + threadIdx.x;
  if (n >= N) return;
  float o0 = t[(size_t)n * 18 + 16] + b2[0];
  float o1 = t[(size_t)n * 18 + 17] + b2[1];
  #pragma unroll
  for (int r = 0; r < NR; r++) {
    int seg = n * NR + r;
    int en = offs[seg], cc = hist[seg];
    float s0 = 0.f, s1 = 0.f;
    for (int i = en - cc; i < en; i++) {
      int s = sorted_src[i];
      s0 += t[(size_t)s * 18 + r * 2];
      s1 += t[(size_t)s * 18 + r * 2 + 1];
    }
    float inv = 1.f / fmaxf((float)cc, 1.f);
    o0 += s0 * inv;
    o1 += s1 * inv;
  }
  out[(size_t)n * 2 + 0] = o0;
  out[(size_t)n * 2 + 1] = o1;
}

extern "C" void kernel_launch(void* const* d_in, const int* in_sizes, int n_in,
                              void* d_out, int out_size, void* d_ws, size_t ws_size,
                              hipStream_t stream) {
  const float* x   = (const float*)d_in[0];
  const int*   ei  = (const int*)d_in[1];
  const int*   et  = (const int*)d_in[2];
  const float* W1  = (const float*)d_in[3];
  const float* Wr1 = (const float*)d_in[4];
  const float* b1  = (const float*)d_in[5];
  const float* W2  = (const float*)d_in[6];
  const float* Wr2 = (const float*)d_in[7];
  const float* b2  = (const float*)d_in[8];
  float* out = (float*)d_out;

  int E = in_sizes[1] / 2;
  int N = in_sizes[0] / DH;
  int S = N * NR;
  const int* src = ei;
  const int* dst = ei + E;

  // ws layout: ints | aggP (packed hi/lo) | WtH WtL | part(2*N*128 f32) | t
  int* hist       = (int*)d_ws;                  // S
  int* offs       = hist + S;                    // S
  int* blksum     = offs + S;                    // 1024
  int* blkoff     = blksum + 1024;               // 1024
  int* sorted_src = blkoff + 1024;               // E
  size_t int_elems = (size_t)S * 2 + 2048 + E;
  int_elems = (int_elems + 3) & ~(size_t)3;      // 16B align
  ushort* aggP = (ushort*)(hist + int_elems);    // S*256
  ushort* WtH  = aggP + (size_t)S * 256;         // 128*1152
  ushort* WtL  = WtH + 128 * 1152;               // 128*1152
  size_t ush_elems = (size_t)S * 256 + 2 * 128 * 1152;
  float* part = (float*)(aggP + ush_elems);      // 2*N*128
  float* t    = part + (size_t)2 * N * DH;       // N*18

  hipMemsetAsync(hist, 0, sizeof(int) * (size_t)S, stream);

  k_hist<<<(E + 255) / 256, 256, 0, stream>>>(dst, et, hist, E);

  int NB = (S + 1023) / 1024;
  k_scan_local<<<NB, 256, 0, stream>>>(hist, offs, blksum, S);
  k_scan_blk<<<1, 512, 0, stream>>>(blksum, blkoff, NB);
  k_scan_add<<<NB, 256, 0, stream>>>(offs, blkoff, S);

  k_scatter_idx<<<(E + 255) / 256, 256, 0, stream>>>(src, dst, et, offs, sorted_src, E);

  k_wsplit<<<dim3(128, 9), 128, 0, stream>>>(W1, Wr1, WtH, WtL);

  k_agg1<<<(S + 3) / 4, 256, 0, stream>>>(offs, hist, sorted_src, x, aggP, S);

  k_gemm1_mfma<<<dim3((N + 63) / 64, 2), 256, 0, stream>>>(aggP, x, WtH, WtL, part, N);

  k_l2trans<<<(N + 3) / 4, 256, 0, stream>>>(part, b1, W2, Wr2, t, N);

  k_out2<<<(N + 255) / 256, 256, 0, stream>>>(offs, hist, sorted_src, t, b2, out, N);
}

// Round 12
// 451.070 us; speedup vs baseline: 1.6704x; 1.0701x over previous
//
#include <hip/hip_runtime.h>
#include <hip/hip_bf16.h>

// RGCN 2-layer forward. CSR counting-sort; layer-1 GEMM via bf16 MFMA.
// Precision: x quantized to bf16 once; agg stored bf16 (hi only, ~2^-9 rel);
// W kept as hi+lo split (2-term MFMA: Ah*Bh + Ah*Bl). Barrier-free GEMM:
// no LDS, B register-direct from L2-resident Wt, A 3-buf / B 2-buf static
// prefetch, all 18 phases unrolled (rule #20: compile-time buffer names).
// L1: aggB[seg][128] = bf16(mean xb[src]); part[kq] = [aggB|xb]_kq @ Wt_kq
// L2: hv = relu(part0+part1+b1) folded into t[n,0:18]; out = gather means of t.

#define NR 8
#define DH 128
#define KCH 18  // kc chunks (32-wide) per split-K block; 36 total

typedef short short8 __attribute__((ext_vector_type(8)));
typedef float f32x4 __attribute__((ext_vector_type(4)));

__device__ inline ushort f2bf(float v) {
  __hip_bfloat16 b = __float2bfloat16(v);
  return *reinterpret_cast<ushort*>(&b);
}
__device__ inline float bf2f(ushort u) {
  __hip_bfloat16 b;
  *reinterpret_cast<ushort*>(&b) = u;
  return __bfloat162float(b);
}
union U128 { uint4 u; short8 s; };

// ---------- counting sort ----------
__global__ __launch_bounds__(256) void k_hist(const int* __restrict__ dst, const int* __restrict__ et,
                                              int* __restrict__ hist, int E) {
  int e = blockIdx.x * 256 + threadIdx.x;
  if (e < E) atomicAdd(&hist[dst[e] * NR + et[e]], 1);
}

__global__ __launch_bounds__(256) void k_scan_local(const int* __restrict__ hist, int* __restrict__ offs,
                                                    int* __restrict__ blksum, int S) {
  __shared__ int tsum[256];
  int tid = threadIdx.x;
  int base = blockIdx.x * 1024 + tid * 4;
  int v[4], tot = 0;
  #pragma unroll
  for (int i = 0; i < 4; i++) { v[i] = (base + i < S) ? hist[base + i] : 0; tot += v[i]; }
  tsum[tid] = tot;
  __syncthreads();
  for (int off = 1; off < 256; off <<= 1) {
    int val = tsum[tid];
    int add = (tid >= off) ? tsum[tid - off] : 0;
    __syncthreads();
    tsum[tid] = val + add;
    __syncthreads();
  }
  int run = tsum[tid] - tot;
  #pragma unroll
  for (int i = 0; i < 4; i++) {
    if (base + i < S) offs[base + i] = run;
    run += v[i];
  }
  if (tid == 255) blksum[blockIdx.x] = tsum[255];
}

__global__ __launch_bounds__(512) void k_scan_blk(const int* __restrict__ blksum, int* __restrict__ blkoff, int NB) {
  __shared__ int s[512];
  int tid = threadIdx.x;
  int v = (tid < NB) ? blksum[tid] : 0;
  s[tid] = v;
  __syncthreads();
  for (int off = 1; off < 512; off <<= 1) {
    int val = s[tid];
    int add = (tid >= off) ? s[tid - off] : 0;
    __syncthreads();
    s[tid] = val + add;
    __syncthreads();
  }
  if (tid < NB) blkoff[tid] = s[tid] - v;
}

__global__ __launch_bounds__(256) void k_scan_add(int* __restrict__ offs, const int* __restrict__ blkoff, int S) {
  int tid = threadIdx.x;
  int base = blockIdx.x * 1024 + tid * 4;
  int add = blkoff[blockIdx.x];
  #pragma unroll
  for (int i = 0; i < 4; i++)
    if (base + i < S) offs[base + i] += add;
}

__global__ __launch_bounds__(256) void k_scatter_idx(const int* __restrict__ src, const int* __restrict__ dst,
                                                     const int* __restrict__ et, int* __restrict__ offs,
                                                     int* __restrict__ sorted_src, int E) {
  int e = blockIdx.x * 256 + threadIdx.x;
  if (e >= E) return;
  int seg = dst[e] * NR + et[e];
  int pos = atomicAdd(&offs[seg], 1);
  sorted_src[pos] = src[e];
}

// ---------- x -> bf16 table ----------
__global__ __launch_bounds__(256) void k_xbf16(const float* __restrict__ x, ushort* __restrict__ xb, int total4) {
  int i = blockIdx.x * 256 + threadIdx.x;
  if (i >= total4) return;
  float4 v = *(const float4*)(x + (size_t)i * 4);
  ushort4 o;
  o.x = f2bf(v.x); o.y = f2bf(v.y); o.z = f2bf(v.z); o.w = f2bf(v.w);
  *(ushort4*)(xb + (size_t)i * 4) = o;
}

// ---------- W split+transpose: Wt[col][k], k in [0,1152) ----------
__global__ __launch_bounds__(128) void k_wsplit(const float* __restrict__ W1, const float* __restrict__ Wr1,
                                                ushort* __restrict__ WtH, ushort* __restrict__ WtL) {
  int c = blockIdx.x;
  int k = blockIdx.y * 128 + threadIdx.x;
  float v = (k < 1024) ? W1[(size_t)k * 128 + c] : Wr1[(size_t)(k - 1024) * 128 + c];
  ushort hi = f2bf(v);
  ushort lo = f2bf(v - bf2f(hi));
  WtH[(size_t)c * 1152 + k] = hi;
  WtL[(size_t)c * 1152 + k] = lo;
}

// ---------- layer 1 aggregate: bf16 gather, f32 accum, bf16 store ----------
__global__ __launch_bounds__(256) void k_agg1(const int* __restrict__ offs, const int* __restrict__ hist,
                                              const int* __restrict__ sorted_src, const ushort* __restrict__ xb,
                                              ushort* __restrict__ aggB, int S) {
  int tid = threadIdx.x;
  int seg = blockIdx.x * 4 + (tid >> 6);
  int lane = tid & 63;
  if (seg >= S) return;
  int end = offs[seg];
  int cnt = hist[seg];
  int st = end - cnt;
  float ax = 0.f, ay = 0.f;
  int i = st;
  for (; i + 4 <= end; i += 4) {
    int s0 = sorted_src[i + 0];
    int s1 = sorted_src[i + 1];
    int s2 = sorted_src[i + 2];
    int s3 = sorted_src[i + 3];
    uint v0 = *(const uint*)(xb + (size_t)s0 * DH + lane * 2);
    uint v1 = *(const uint*)(xb + (size_t)s1 * DH + lane * 2);
    uint v2 = *(const uint*)(xb + (size_t)s2 * DH + lane * 2);
    uint v3 = *(const uint*)(xb + (size_t)s3 * DH + lane * 2);
    ax += bf2f((ushort)(v0 & 0xffff)) + bf2f((ushort)(v1 & 0xffff)) +
          bf2f((ushort)(v2 & 0xffff)) + bf2f((ushort)(v3 & 0xffff));
    ay += bf2f((ushort)(v0 >> 16)) + bf2f((ushort)(v1 >> 16)) +
          bf2f((ushort)(v2 >> 16)) + bf2f((ushort)(v3 >> 16));
  }
  for (; i < end; i++) {
    int s = sorted_src[i];
    uint v = *(const uint*)(xb + (size_t)s * DH + lane * 2);
    ax += bf2f((ushort)(v & 0xffff));
    ay += bf2f((ushort)(v >> 16));
  }
  float inv = 1.f / fmaxf((float)cnt, 1.f);
  ushort2 hv;
  hv.x = f2bf(ax * inv);
  hv.y = f2bf(ay * inv);
  *(ushort2*)(aggB + (size_t)seg * DH + lane * 2) = hv;
}

// ---------- layer 1 MFMA GEMM: barrier-free, no LDS, split-K=2, BM=64 ----------
// 256 thr = 4 waves (2 wr x 2 wc), block tile 64x128, wave tile 32x64 (2x4 frags).
// A: bf16 aggB/xb direct (1 uint4 per ft per phase), 3-buffer prefetch.
// B: register-direct hi+lo from Wt (L2-resident), 2-buffer prefetch.
// 2-term: acc += Ah*Bh + Ah*Bl. All KCH=18 phases unrolled, static names.
__global__ __launch_bounds__(256) void k_gemm1_mfma(
    const ushort* __restrict__ aggB, const ushort* __restrict__ xb,
    const ushort* __restrict__ WtH, const ushort* __restrict__ WtL,
    float* __restrict__ part, int N) {
  int tid = threadIdx.x;
  int w = tid >> 6, lane = tid & 63;
  int wr = w >> 1, wc = w & 1;
  int n0 = blockIdx.x * 64;
  int k0 = blockIdx.y * KCH;

  int frow = lane & 15;
  int fk8 = (lane >> 4) * 8;

  f32x4 acc[2][4];
  #pragma unroll
  for (int i = 0; i < 2; i++)
    #pragma unroll
    for (int j = 0; j < 4; j++) acc[i][j] = (f32x4){0.f, 0.f, 0.f, 0.f};

  int arow[2];
  #pragma unroll
  for (int ft = 0; ft < 2; ft++) {
    int r = n0 + wr * 32 + ft * 16 + frow;
    arow[ft] = (r < N) ? r : (N - 1);  // clamp: OOB rows compute garbage, never stored
  }
  int baseB[4];
  #pragma unroll
  for (int ct = 0; ct < 4; ct++) {
    int colW = wc * 64 + ct * 16 + frow;
    baseB[ct] = colW * 1152 + fk8;
  }

  uint4 pa0[2], pa1[2], pa2[2];  // A: [ft], static names (rule #20)
  uint4 pb0[4][2], pb1[4][2];    // B: [ct][plane]

  #define LOADA(KC, P)                                                        \
    if ((KC) < 32) {                                                          \
      _Pragma("unroll")                                                       \
      for (int ft = 0; ft < 2; ft++)                                          \
        P[ft] = *(const uint4*)(aggB + (size_t)arow[ft] * 1024 + (KC) * 32 + fk8); \
    } else {                                                                  \
      _Pragma("unroll")                                                       \
      for (int ft = 0; ft < 2; ft++)                                          \
        P[ft] = *(const uint4*)(xb + (size_t)arow[ft] * 128 + ((KC) - 32) * 32 + fk8); \
    }

  #define LOADB(KC, P)                                                        \
    {                                                                         \
      _Pragma("unroll")                                                       \
      for (int ct = 0; ct < 4; ct++) {                                        \
        P[ct][0] = *(const uint4*)(WtH + baseB[ct] + (KC) * 32);              \
        P[ct][1] = *(const uint4*)(WtL + baseB[ct] + (KC) * 32);              \
      }                                                                       \
    }

  #define PHASE(I, PAU, PAF, PBU, PBF)                                        \
    {                                                                         \
      if ((I) + 2 < KCH) { LOADA(k0 + (I) + 2, PAF); }                        \
      if ((I) + 1 < KCH) { LOADB(k0 + (I) + 1, PBF); }                        \
      U128 a0_, a1_;                                                          \
      a0_.u = PAU[0];                                                         \
      a1_.u = PAU[1];                                                         \
      _Pragma("unroll")                                                       \
      for (int ct = 0; ct < 4; ct++) {                                        \
        U128 bh_, bl_;                                                        \
        bh_.u = PBU[ct][0]; bl_.u = PBU[ct][1];                               \
        const short8 bH = bh_.s;                                              \
        const short8 bL = bl_.s;                                              \
        acc[0][ct] = __builtin_amdgcn_mfma_f32_16x16x32_bf16(a0_.s, bH, acc[0][ct], 0, 0, 0); \
        acc[0][ct] = __builtin_amdgcn_mfma_f32_16x16x32_bf16(a0_.s, bL, acc[0][ct], 0, 0, 0); \
        acc[1][ct] = __builtin_amdgcn_mfma_f32_16x16x32_bf16(a1_.s, bH, acc[1][ct], 0, 0, 0); \
        acc[1][ct] = __builtin_amdgcn_mfma_f32_16x16x32_bf16(a1_.s, bL, acc[1][ct], 0, 0, 0); \
      }                                                                       \
    }

  // prologue: A 2 buffers ahead, B 1 buffer ahead
  LOADA(k0, pa0);
  LOADA(k0 + 1, pa1);
  LOADB(k0, pb0);

  PHASE(0,  pa0, pa2, pb0, pb1)
  PHASE(1,  pa1, pa0, pb1, pb0)
  PHASE(2,  pa2, pa1, pb0, pb1)
  PHASE(3,  pa0, pa2, pb1, pb0)
  PHASE(4,  pa1, pa0, pb0, pb1)
  PHASE(5,  pa2, pa1, pb1, pb0)
  PHASE(6,  pa0, pa2, pb0, pb1)
  PHASE(7,  pa1, pa0, pb1, pb0)
  PHASE(8,  pa2, pa1, pb0, pb1)
  PHASE(9,  pa0, pa2, pb1, pb0)
  PHASE(10, pa1, pa0, pb0, pb1)
  PHASE(11, pa2, pa1, pb1, pb0)
  PHASE(12, pa0, pa2, pb0, pb1)
  PHASE(13, pa1, pa0, pb1, pb0)
  PHASE(14, pa2, pa1, pb0, pb1)
  PHASE(15, pa0, pa2, pb1, pb0)
  PHASE(16, pa1, pa0, pb0, pb1)
  PHASE(17, pa2, pa1, pb1, pb0)

  #undef LOADA
  #undef LOADB
  #undef PHASE

  // epilogue: raw partial sums; D layout col=lane&15, row=(lane>>4)*4+q
  float* po = part + (size_t)blockIdx.y * N * DH;
  int rbase = n0 + wr * 32 + (lane >> 4) * 4;
  #pragma unroll
  for (int ft = 0; ft < 2; ft++) {
    #pragma unroll
    for (int ct = 0; ct < 4; ct++) {
      int C = wc * 64 + ct * 16 + frow;
      #pragma unroll
      for (int q = 0; q < 4; q++) {
        int R = rbase + ft * 16 + q;
        if (R < N) po[(size_t)R * DH + C] = acc[ft][ct][q];
      }
    }
  }
}

// ---------- layer-2 transform (fused split-K combine + bias + relu) ----------
__global__ __launch_bounds__(256) void k_l2trans(const float* __restrict__ part, const float* __restrict__ b1,
                                                 const float* __restrict__ W2, const float* __restrict__ Wr2,
                                                 float* __restrict__ t, int N) {
  __shared__ float Wt[18 * 128];
  int tid = threadIdx.x;
  for (int i = tid; i < 2304; i += 256) {
    float v; int oc, d;
    if (i < 2048) { int r = i >> 8, rem = i & 255; d = rem >> 1; int c = rem & 1; oc = r * 2 + c; v = W2[i]; }
    else { int i2 = i - 2048; d = i2 >> 1; int c = i2 & 1; oc = 16 + c; v = Wr2[i2]; }
    Wt[oc * 128 + d] = v;
  }
  __syncthreads();
  int node = blockIdx.x * 4 + (tid >> 6);
  int lane = tid & 63;
  if (node >= N) return;
  size_t NP = (size_t)N * DH;
  float2 a0 = *(const float2*)(part + (size_t)node * DH + lane * 2);
  float2 a1 = *(const float2*)(part + NP + (size_t)node * DH + lane * 2);
  float2 bb = *(const float2*)(b1 + lane * 2);
  float2 hv;
  hv.x = fmaxf(a0.x + a1.x + bb.x, 0.f);
  hv.y = fmaxf(a0.y + a1.y + bb.y, 0.f);
  #pragma unroll
  for (int oc = 0; oc < 18; oc++) {
    float2 w = *(const float2*)(Wt + oc * 128 + lane * 2);
    float p = hv.x * w.x + hv.y * w.y;
    p += __shfl_xor(p, 32); p += __shfl_xor(p, 16); p += __shfl_xor(p, 8);
    p += __shfl_xor(p, 4);  p += __shfl_xor(p, 2);  p += __shfl_xor(p, 1);
    if (lane == 0) t[(size_t)node * 18 + oc] = p;
  }
}

// ---------- output: gather tiny t values per segment ----------
__global__ __launch_bounds__(256) void k_out2(const int* __restrict__ offs, const int* __restrict__ hist,
                                              const int* __restrict__ sorted_src, const float* __restrict__ t,
                                              const float* __restrict__ b2, float* __restrict__ out, int N) {
  int n = blockIdx.x * 256 + threadIdx.x;
  if (n >= N) return;
  float o0 = t[(size_t)n * 18 + 16] + b2[0];
  float o1 = t[(size_t)n * 18 + 17] + b2[1];
  #pragma unroll
  for (int r = 0; r < NR; r++) {
    int seg = n * NR + r;
    int en = offs[seg], cc = hist[seg];
    float s0 = 0.f, s1 = 0.f;
    for (int i = en - cc; i < en; i++) {
      int s = sorted_src[i];
      s0 += t[(size_t)s * 18 + r * 2];
      s1 += t[(size_t)s * 18 + r * 2 + 1];
    }
    float inv = 1.f / fmaxf((float)cc, 1.f);
    o0 += s0 * inv;
    o1 += s1 * inv;
  }
  out[(size_t)n * 2 + 0] = o0;
  out[(size_t)n * 2 + 1] = o1;
}

extern "C" void kernel_launch(void* const* d_in, const int* in_sizes, int n_in,
                              void* d_out, int out_size, void* d_ws, size_t ws_size,
                              hipStream_t stream) {
  const float* x   = (const float*)d_in[0];
  const int*   ei  = (const int*)d_in[1];
  const int*   et  = (const int*)d_in[2];
  const float* W1  = (const float*)d_in[3];
  const float* Wr1 = (const float*)d_in[4];
  const float* b1  = (const float*)d_in[5];
  const float* W2  = (const float*)d_in[6];
  const float* Wr2 = (const float*)d_in[7];
  const float* b2  = (const float*)d_in[8];
  float* out = (float*)d_out;

  int E = in_sizes[1] / 2;
  int N = in_sizes[0] / DH;
  int S = N * NR;
  const int* src = ei;
  const int* dst = ei + E;

  // ws layout: ints | aggB (bf16) | xb (bf16) | WtH WtL | part(2*N*128 f32) | t
  int* hist       = (int*)d_ws;                  // S
  int* offs       = hist + S;                    // S
  int* blksum     = offs + S;                    // 1024
  int* blkoff     = blksum + 1024;               // 1024
  int* sorted_src = blkoff + 1024;               // E
  size_t int_elems = (size_t)S * 2 + 2048 + E;
  int_elems = (int_elems + 3) & ~(size_t)3;      // 16B align
  ushort* aggB = (ushort*)(hist + int_elems);    // S*128
  ushort* xb   = aggB + (size_t)S * DH;          // N*128
  ushort* WtH  = xb + (size_t)N * DH;            // 128*1152
  ushort* WtL  = WtH + 128 * 1152;               // 128*1152
  size_t ush_elems = (size_t)S * DH + (size_t)N * DH + 2 * 128 * 1152;
  float* part = (float*)(aggB + ush_elems);      // 2*N*128
  float* t    = part + (size_t)2 * N * DH;       // N*18

  hipMemsetAsync(hist, 0, sizeof(int) * (size_t)S, stream);

  k_hist<<<(E + 255) / 256, 256, 0, stream>>>(dst, et, hist, E);

  int NB = (S + 1023) / 1024;
  k_scan_local<<<NB, 256, 0, stream>>>(hist, offs, blksum, S);
  k_scan_blk<<<1, 512, 0, stream>>>(blksum, blkoff, NB);
  k_scan_add<<<NB, 256, 0, stream>>>(offs, blkoff, S);

  k_scatter_idx<<<(E + 255) / 256, 256, 0, stream>>>(src, dst, et, offs, sorted_src, E);

  int total4 = N * DH / 4;
  k_xbf16<<<(total4 + 255) / 256, 256, 0, stream>>>(x, xb, total4);

  k_wsplit<<<dim3(128, 9), 128, 0, stream>>>(W1, Wr1, WtH, WtL);

  k_agg1<<<(S + 3) / 4, 256, 0, stream>>>(offs, hist, sorted_src, xb, aggB, S);

  k_gemm1_mfma<<<dim3((N + 63) / 64, 2), 256, 0, stream>>>(aggB, xb, WtH, WtL, part, N);

  k_l2trans<<<(N + 3) / 4, 256, 0, stream>>>(part, b1, W2, Wr2, t, N);

  k_out2<<<(N + 255) / 256, 256, 0, stream>>>(offs, hist, sorted_src, t, b2, out, N);
}

// Round 13
// 415.911 us; speedup vs baseline: 1.8116x; 1.0845x over previous
//
#include <hip/hip_runtime.h>
#include <hip/hip_bf16.h>

// RGCN 2-layer forward. Transform-then-aggregate on BOTH layers (mean commutes
// with the linear maps).
// L1: Y[n,0:1152] = xb[n] @ [W_r0..W_r7 | Wroot]  (dense bf16 MFMA GEMM,
//       A = 12.8MB xb reused 9x; 2-term W hi+lo; Y stored bf16)
//     h[n] = relu(sum_r invc[n,r] * sum_{e in (n,r)} Y[src_e, r*128:+128]
//                 + Y[n,1024:1152] + b1)          (per-node wave gather)
// L2: t[n,0:18] = h[n] @ [W2_r(:,0:2).. | Wr2]; out = gather means of t.

#define NR 8
#define DH 128

typedef short short8 __attribute__((ext_vector_type(8)));
typedef float f32x4 __attribute__((ext_vector_type(4)));

__device__ inline ushort f2bf(float v) {
  __hip_bfloat16 b = __float2bfloat16(v);
  return *reinterpret_cast<ushort*>(&b);
}
__device__ inline float bf2f(ushort u) {
  __hip_bfloat16 b;
  *reinterpret_cast<ushort*>(&b) = u;
  return __bfloat162float(b);
}
union U128 { uint4 u; short8 s; };

// ---------- counting sort ----------
__global__ __launch_bounds__(256) void k_hist(const int* __restrict__ dst, const int* __restrict__ et,
                                              int* __restrict__ hist, int E) {
  int e = blockIdx.x * 256 + threadIdx.x;
  if (e < E) atomicAdd(&hist[dst[e] * NR + et[e]], 1);
}

__global__ __launch_bounds__(256) void k_scan_local(const int* __restrict__ hist, int* __restrict__ offs,
                                                    int* __restrict__ blksum, int S) {
  __shared__ int tsum[256];
  int tid = threadIdx.x;
  int base = blockIdx.x * 1024 + tid * 4;
  int v[4], tot = 0;
  #pragma unroll
  for (int i = 0; i < 4; i++) { v[i] = (base + i < S) ? hist[base + i] : 0; tot += v[i]; }
  tsum[tid] = tot;
  __syncthreads();
  for (int off = 1; off < 256; off <<= 1) {
    int val = tsum[tid];
    int add = (tid >= off) ? tsum[tid - off] : 0;
    __syncthreads();
    tsum[tid] = val + add;
    __syncthreads();
  }
  int run = tsum[tid] - tot;
  #pragma unroll
  for (int i = 0; i < 4; i++) {
    if (base + i < S) offs[base + i] = run;
    run += v[i];
  }
  if (tid == 255) blksum[blockIdx.x] = tsum[255];
}

__global__ __launch_bounds__(512) void k_scan_blk(const int* __restrict__ blksum, int* __restrict__ blkoff, int NB) {
  __shared__ int s[512];
  int tid = threadIdx.x;
  int v = (tid < NB) ? blksum[tid] : 0;
  s[tid] = v;
  __syncthreads();
  for (int off = 1; off < 512; off <<= 1) {
    int val = s[tid];
    int add = (tid >= off) ? s[tid - off] : 0;
    __syncthreads();
    s[tid] = val + add;
    __syncthreads();
  }
  if (tid < NB) blkoff[tid] = s[tid] - v;
}

__global__ __launch_bounds__(256) void k_scan_add(int* __restrict__ offs, const int* __restrict__ blkoff, int S) {
  int tid = threadIdx.x;
  int base = blockIdx.x * 1024 + tid * 4;
  int add = blkoff[blockIdx.x];
  #pragma unroll
  for (int i = 0; i < 4; i++)
    if (base + i < S) offs[base + i] += add;
}

__global__ __launch_bounds__(256) void k_scatter_idx(const int* __restrict__ src, const int* __restrict__ dst,
                                                     const int* __restrict__ et, int* __restrict__ offs,
                                                     int* __restrict__ sorted_src, int E) {
  int e = blockIdx.x * 256 + threadIdx.x;
  if (e >= E) return;
  int seg = dst[e] * NR + et[e];
  int pos = atomicAdd(&offs[seg], 1);
  sorted_src[pos] = src[e];
}

// ---------- x -> bf16 table ----------
__global__ __launch_bounds__(256) void k_xbf16(const float* __restrict__ x, ushort* __restrict__ xb, int total4) {
  int i = blockIdx.x * 256 + threadIdx.x;
  if (i >= total4) return;
  float4 v = *(const float4*)(x + (size_t)i * 4);
  ushort4 o;
  o.x = f2bf(v.x); o.y = f2bf(v.y); o.z = f2bf(v.z); o.w = f2bf(v.w);
  *(ushort4*)(xb + (size_t)i * 4) = o;
}

// ---------- W split+transpose: Wt[c][k], c in [0,1152) (8 rels x 128 | root), k in [0,128) ----------
__global__ __launch_bounds__(128) void k_wsplit(const float* __restrict__ W1, const float* __restrict__ Wr1,
                                                ushort* __restrict__ WtH, ushort* __restrict__ WtL) {
  int c = blockIdx.x;          // 0..1151
  int k = threadIdx.x;         // 0..127
  float v;
  if (c < 1024) {
    int r = c >> 7, col = c & 127;
    v = W1[((size_t)r * 128 + k) * 128 + col];
  } else {
    v = Wr1[(size_t)k * 128 + (c - 1024)];
  }
  ushort hi = f2bf(v);
  ushort lo = f2bf(v - bf2f(hi));
  WtH[(size_t)c * 128 + k] = hi;
  WtL[(size_t)c * 128 + k] = lo;
}

// ---------- dense GEMM: Y[N,1152] = xb[N,128] @ Wt^T, bf16 out ----------
// grid (ceil(N/64), 9): blockIdx.y = 128-col tile. 256 thr = 4 waves (2x2),
// wave tile 32x64 (2 ft x 4 ct frags). K = 4 chunks of 32, A fully prefetched
// (pa0..pa3 static names, rule #20), B hi/lo double-buffered from L2-resident Wt.
// 2-term MFMA: acc += A*Bh + A*Bl. Barrier-free, no LDS.
__global__ __launch_bounds__(256) void k_gemm_dense(
    const ushort* __restrict__ xb,
    const ushort* __restrict__ WtH, const ushort* __restrict__ WtL,
    ushort* __restrict__ Y, int N) {
  int tid = threadIdx.x;
  int w = tid >> 6, lane = tid & 63;
  int wr = w >> 1, wc = w & 1;
  int n0 = blockIdx.x * 64;
  int colbase = blockIdx.y * 128;

  int frow = lane & 15;
  int fk8 = (lane >> 4) * 8;

  f32x4 acc[2][4];
  #pragma unroll
  for (int i = 0; i < 2; i++)
    #pragma unroll
    for (int j = 0; j < 4; j++) acc[i][j] = (f32x4){0.f, 0.f, 0.f, 0.f};

  int arow[2];
  #pragma unroll
  for (int ft = 0; ft < 2; ft++) {
    int r = n0 + wr * 32 + ft * 16 + frow;
    arow[ft] = (r < N) ? r : (N - 1);  // clamp: OOB rows compute garbage, never stored
  }
  int baseB[4];
  #pragma unroll
  for (int ct = 0; ct < 4; ct++) {
    int colW = colbase + wc * 64 + ct * 16 + frow;
    baseB[ct] = colW * 128 + fk8;
  }

  uint4 pa0[2], pa1[2], pa2[2], pa3[2];  // A: all 4 K-chunks up front
  uint4 pb0[4][2], pb1[4][2];            // B: [ct][plane], double-buffered

  #define LOADA(KC, P)                                                        \
    {                                                                         \
      _Pragma("unroll")                                                       \
      for (int ft = 0; ft < 2; ft++)                                          \
        P[ft] = *(const uint4*)(xb + (size_t)arow[ft] * 128 + (KC) * 32 + fk8); \
    }
  #define LOADB(KC, P)                                                       \
    {                                                                         \
      _Pragma("unroll")                                                       \
      for (int ct = 0; ct < 4; ct++) {                                        \
        P[ct][0] = *(const uint4*)(WtH + baseB[ct] + (KC) * 32);              \
        P[ct][1] = *(const uint4*)(WtL + baseB[ct] + (KC) * 32);              \
      }                                                                       \
    }
  #define PHASE(I, PAU, PBU, PBF)                                            \
    {                                                                         \
      if ((I) + 1 < 4) { LOADB((I) + 1, PBF); }                               \
      U128 a0_, a1_;                                                          \
      a0_.u = PAU[0];                                                         \
      a1_.u = PAU[1];                                                         \
      _Pragma("unroll")                                                       \
      for (int ct = 0; ct < 4; ct++) {                                        \
        U128 bh_, bl_;                                                        \
        bh_.u = PBU[ct][0]; bl_.u = PBU[ct][1];                               \
        const short8 bH = bh_.s;                                              \
        const short8 bL = bl_.s;                                              \
        acc[0][ct] = __builtin_amdgcn_mfma_f32_16x16x32_bf16(a0_.s, bH, acc[0][ct], 0, 0, 0); \
        acc[0][ct] = __builtin_amdgcn_mfma_f32_16x16x32_bf16(a0_.s, bL, acc[0][ct], 0, 0, 0); \
        acc[1][ct] = __builtin_amdgcn_mfma_f32_16x16x32_bf16(a1_.s, bH, acc[1][ct], 0, 0, 0); \
        acc[1][ct] = __builtin_amdgcn_mfma_f32_16x16x32_bf16(a1_.s, bL, acc[1][ct], 0, 0, 0); \
      }                                                                       \
    }

  LOADA(0, pa0);
  LOADA(1, pa1);
  LOADA(2, pa2);
  LOADA(3, pa3);
  LOADB(0, pb0);

  PHASE(0, pa0, pb0, pb1)
  PHASE(1, pa1, pb1, pb0)
  PHASE(2, pa2, pb0, pb1)
  PHASE(3, pa3, pb1, pb0)

  #undef LOADA
  #undef LOADB
  #undef PHASE

  // epilogue: Y bf16; D layout col=lane&15, row=(lane>>4)*4+q
  int rbase = n0 + wr * 32 + (lane >> 4) * 4;
  #pragma unroll
  for (int ft = 0; ft < 2; ft++) {
    #pragma unroll
    for (int ct = 0; ct < 4; ct++) {
      int C = colbase + wc * 64 + ct * 16 + frow;
      #pragma unroll
      for (int q = 0; q < 4; q++) {
        int R = rbase + ft * 16 + q;
        if (R < N) Y[(size_t)R * 1152 + C] = f2bf(acc[ft][ct][q]);
      }
    }
  }
}

// ---------- h gather: h[n] = relu(Yroot + b1 + sum_r invc * sum_e Y[src_e, r*128:]) ----------
__global__ __launch_bounds__(256) void k_hgather(const int* __restrict__ offs, const int* __restrict__ hist,
                                                 const int* __restrict__ sorted_src, const ushort* __restrict__ Y,
                                                 const float* __restrict__ b1, float* __restrict__ h, int N) {
  int tid = threadIdx.x;
  int node = blockIdx.x * 4 + (tid >> 6);
  int lane = tid & 63;
  if (node >= N) return;
  int c0 = lane * 2;
  uint vroot = *(const uint*)(Y + (size_t)node * 1152 + 1024 + c0);
  float2 bb = *(const float2*)(b1 + c0);
  float ax = bf2f((ushort)(vroot & 0xffff)) + bb.x;
  float ay = bf2f((ushort)(vroot >> 16)) + bb.y;
  #pragma unroll
  for (int r = 0; r < NR; r++) {
    int seg = node * NR + r;
    int en = offs[seg];
    int cc = hist[seg];
    int st = en - cc;
    float sx = 0.f, sy = 0.f;
    int i = st;
    for (; i + 4 <= en; i += 4) {
      int s0 = sorted_src[i + 0];
      int s1 = sorted_src[i + 1];
      int s2 = sorted_src[i + 2];
      int s3 = sorted_src[i + 3];
      uint v0 = *(const uint*)(Y + (size_t)s0 * 1152 + r * 128 + c0);
      uint v1 = *(const uint*)(Y + (size_t)s1 * 1152 + r * 128 + c0);
      uint v2 = *(const uint*)(Y + (size_t)s2 * 1152 + r * 128 + c0);
      uint v3 = *(const uint*)(Y + (size_t)s3 * 1152 + r * 128 + c0);
      sx += bf2f((ushort)(v0 & 0xffff)) + bf2f((ushort)(v1 & 0xffff)) +
            bf2f((ushort)(v2 & 0xffff)) + bf2f((ushort)(v3 & 0xffff));
      sy += bf2f((ushort)(v0 >> 16)) + bf2f((ushort)(v1 >> 16)) +
            bf2f((ushort)(v2 >> 16)) + bf2f((ushort)(v3 >> 16));
    }
    for (; i < en; i++) {
      int s = sorted_src[i];
      uint v = *(const uint*)(Y + (size_t)s * 1152 + r * 128 + c0);
      sx += bf2f((ushort)(v & 0xffff));
      sy += bf2f((ushort)(v >> 16));
    }
    float inv = 1.f / fmaxf((float)cc, 1.f);
    ax += sx * inv;
    ay += sy * inv;
  }
  float2 o;
  o.x = fmaxf(ax, 0.f);
  o.y = fmaxf(ay, 0.f);
  *(float2*)(h + (size_t)node * DH + c0) = o;
}

// ---------- layer-2 transform: t[n,0:18] = h[n] @ [W2_r(:,0:2)... | Wr2] ----------
__global__ __launch_bounds__(256) void k_l2trans(const float* __restrict__ h,
                                                 const float* __restrict__ W2, const float* __restrict__ Wr2,
                                                 float* __restrict__ t, int N) {
  __shared__ float Wt[18 * 128];
  int tid = threadIdx.x;
  for (int i = tid; i < 2304; i += 256) {
    float v; int oc, d;
    if (i < 2048) { int r = i >> 8, rem = i & 255; d = rem >> 1; int c = rem & 1; oc = r * 2 + c; v = W2[i]; }
    else { int i2 = i - 2048; d = i2 >> 1; int c = i2 & 1; oc = 16 + c; v = Wr2[i2]; }
    Wt[oc * 128 + d] = v;
  }
  __syncthreads();
  int node = blockIdx.x * 4 + (tid >> 6);
  int lane = tid & 63;
  if (node >= N) return;
  float2 hv = *(const float2*)(h + (size_t)node * DH + lane * 2);
  #pragma unroll
  for (int oc = 0; oc < 18; oc++) {
    float2 w = *(const float2*)(Wt + oc * 128 + lane * 2);
    float p = hv.x * w.x + hv.y * w.y;
    p += __shfl_xor(p, 32); p += __shfl_xor(p, 16); p += __shfl_xor(p, 8);
    p += __shfl_xor(p, 4);  p += __shfl_xor(p, 2);  p += __shfl_xor(p, 1);
    if (lane == 0) t[(size_t)node * 18 + oc] = p;
  }
}

// ---------- output: gather tiny t values per segment ----------
__global__ __launch_bounds__(256) void k_out2(const int* __restrict__ offs, const int* __restrict__ hist,
                                              const int* __restrict__ sorted_src, const float* __restrict__ t,
                                              const float* __restrict__ b2, float* __restrict__ out, int N) {
  int n = blockIdx.x * 256 + threadIdx.x;
  if (n >= N) return;
  float o0 = t[(size_t)n * 18 + 16] + b2[0];
  float o1 = t[(size_t)n * 18 + 17] + b2[1];
  #pragma unroll
  for (int r = 0; r < NR; r++) {
    int seg = n * NR + r;
    int en = offs[seg], cc = hist[seg];
    float s0 = 0.f, s1 = 0.f;
    for (int i = en - cc; i < en; i++) {
      int s = sorted_src[i];
      s0 += t[(size_t)s * 18 + r * 2];
      s1 += t[(size_t)s * 18 + r * 2 + 1];
    }
    float inv = 1.f / fmaxf((float)cc, 1.f);
    o0 += s0 * inv;
    o1 += s1 * inv;
  }
  out[(size_t)n * 2 + 0] = o0;
  out[(size_t)n * 2 + 1] = o1;
}

extern "C" void kernel_launch(void* const* d_in, const int* in_sizes, int n_in,
                              void* d_out, int out_size, void* d_ws, size_t ws_size,
                              hipStream_t stream) {
  const float* x   = (const float*)d_in[0];
  const int*   ei  = (const int*)d_in[1];
  const int*   et  = (const int*)d_in[2];
  const float* W1  = (const float*)d_in[3];
  const float* Wr1 = (const float*)d_in[4];
  const float* b1  = (const float*)d_in[5];
  const float* W2  = (const float*)d_in[6];
  const float* Wr2 = (const float*)d_in[7];
  const float* b2  = (const float*)d_in[8];
  float* out = (float*)d_out;

  int E = in_sizes[1] / 2;
  int N = in_sizes[0] / DH;
  int S = N * NR;
  const int* src = ei;
  const int* dst = ei + E;

  // ws layout: ints | xb | WtH WtL | Y (bf16, N*1152) | h (f32) | t
  int* hist       = (int*)d_ws;                  // S
  int* offs       = hist + S;                    // S
  int* blksum     = offs + S;                    // 1024
  int* blkoff     = blksum + 1024;               // 1024
  int* sorted_src = blkoff + 1024;               // E
  size_t int_elems = (size_t)S * 2 + 2048 + E;
  int_elems = (int_elems + 3) & ~(size_t)3;      // 16B align
  ushort* xb  = (ushort*)(hist + int_elems);     // N*128
  ushort* WtH = xb + (size_t)N * DH;             // 1152*128
  ushort* WtL = WtH + 1152 * 128;                // 1152*128
  ushort* Y   = WtL + 1152 * 128;                // N*1152
  size_t ush_elems = (size_t)N * DH + 2 * 1152 * 128 + (size_t)N * 1152;
  ush_elems = (ush_elems + 1) & ~(size_t)1;      // float align
  float* h = (float*)(xb + ush_elems);           // N*128
  float* t = h + (size_t)N * DH;                 // N*18

  hipMemsetAsync(hist, 0, sizeof(int) * (size_t)S, stream);

  k_hist<<<(E + 255) / 256, 256, 0, stream>>>(dst, et, hist, E);

  int NB = (S + 1023) / 1024;
  k_scan_local<<<NB, 256, 0, stream>>>(hist, offs, blksum, S);
  k_scan_blk<<<1, 512, 0, stream>>>(blksum, blkoff, NB);
  k_scan_add<<<NB, 256, 0, stream>>>(offs, blkoff, S);

  k_scatter_idx<<<(E + 255) / 256, 256, 0, stream>>>(src, dst, et, offs, sorted_src, E);

  int total4 = N * DH / 4;
  k_xbf16<<<(total4 + 255) / 256, 256, 0, stream>>>(x, xb, total4);

  k_wsplit<<<1152, 128, 0, stream>>>(W1, Wr1, WtH, WtL);

  k_gemm_dense<<<dim3((N + 63) / 64, 9), 256, 0, stream>>>(xb, WtH, WtL, Y, N);

  k_hgather<<<(N + 3) / 4, 256, 0, stream>>>(offs, hist, sorted_src, Y, b1, h, N);

  k_l2trans<<<(N + 3) / 4, 256, 0, stream>>>(h, W2, Wr2, t, N);

  k_out2<<<(N + 255) / 256, 256, 0, stream>>>(offs, hist, sorted_src, t, b2, out, N);
}

// Round 14
// 376.376 us; speedup vs baseline: 2.0019x; 1.1050x over previous
//
#include <hip/hip_runtime.h>
#include <hip/hip_bf16.h>

// RGCN 2-layer forward. Transform-then-aggregate on BOTH layers.
// L1: Y[n,0:1152] = xb[n] @ [W_r0..W_r7 | Wroot]  (dense bf16 MFMA GEMM)
//     Operand-swapped MFMA (A=W, B=xb): D rows = Y-cols -> packed ushort4 stores.
//     Per block: xb frags register-resident, wave loops 9 C-chunks (576 MFMA/wave).
//     h[n] = relu(sum_r invc * sum_e Y[src_e, r*128:] + Y[n,1024:] + b1) (wave gather)
// L2: t[n,0:18] = h[n] @ [W2_r(:,0:2).. | Wr2]; out = gather means of t.

#define NR 8
#define DH 128

typedef short short8 __attribute__((ext_vector_type(8)));
typedef float f32x4 __attribute__((ext_vector_type(4)));

__device__ inline ushort f2bf(float v) {
  __hip_bfloat16 b = __float2bfloat16(v);
  return *reinterpret_cast<ushort*>(&b);
}
__device__ inline float bf2f(ushort u) {
  __hip_bfloat16 b;
  *reinterpret_cast<ushort*>(&b) = u;
  return __bfloat162float(b);
}
union U128 { uint4 u; short8 s; };

// ---------- counting sort ----------
__global__ __launch_bounds__(256) void k_hist(const int* __restrict__ dst, const int* __restrict__ et,
                                              int* __restrict__ hist, int E) {
  int e = blockIdx.x * 256 + threadIdx.x;
  if (e < E) atomicAdd(&hist[dst[e] * NR + et[e]], 1);
}

__global__ __launch_bounds__(256) void k_scan_local(const int* __restrict__ hist, int* __restrict__ offs,
                                                    int* __restrict__ blksum, int S) {
  __shared__ int tsum[256];
  int tid = threadIdx.x;
  int base = blockIdx.x * 1024 + tid * 4;
  int v[4], tot = 0;
  #pragma unroll
  for (int i = 0; i < 4; i++) { v[i] = (base + i < S) ? hist[base + i] : 0; tot += v[i]; }
  tsum[tid] = tot;
  __syncthreads();
  for (int off = 1; off < 256; off <<= 1) {
    int val = tsum[tid];
    int add = (tid >= off) ? tsum[tid - off] : 0;
    __syncthreads();
    tsum[tid] = val + add;
    __syncthreads();
  }
  int run = tsum[tid] - tot;
  #pragma unroll
  for (int i = 0; i < 4; i++) {
    if (base + i < S) offs[base + i] = run;
    run += v[i];
  }
  if (tid == 255) blksum[blockIdx.x] = tsum[255];
}

__global__ __launch_bounds__(512) void k_scan_blk(const int* __restrict__ blksum, int* __restrict__ blkoff, int NB) {
  __shared__ int s[512];
  int tid = threadIdx.x;
  int v = (tid < NB) ? blksum[tid] : 0;
  s[tid] = v;
  __syncthreads();
  for (int off = 1; off < 512; off <<= 1) {
    int val = s[tid];
    int add = (tid >= off) ? s[tid - off] : 0;
    __syncthreads();
    s[tid] = val + add;
    __syncthreads();
  }
  if (tid < NB) blkoff[tid] = s[tid] - v;
}

__global__ __launch_bounds__(256) void k_scan_add(int* __restrict__ offs, const int* __restrict__ blkoff, int S) {
  int tid = threadIdx.x;
  int base = blockIdx.x * 1024 + tid * 4;
  int add = blkoff[blockIdx.x];
  #pragma unroll
  for (int i = 0; i < 4; i++)
    if (base + i < S) offs[base + i] += add;
}

__global__ __launch_bounds__(256) void k_scatter_idx(const int* __restrict__ src, const int* __restrict__ dst,
                                                     const int* __restrict__ et, int* __restrict__ offs,
                                                     int* __restrict__ sorted_src, int E) {
  int e = blockIdx.x * 256 + threadIdx.x;
  if (e >= E) return;
  int seg = dst[e] * NR + et[e];
  int pos = atomicAdd(&offs[seg], 1);
  sorted_src[pos] = src[e];
}

// ---------- x -> bf16 table ----------
__global__ __launch_bounds__(256) void k_xbf16(const float* __restrict__ x, ushort* __restrict__ xb, int total4) {
  int i = blockIdx.x * 256 + threadIdx.x;
  if (i >= total4) return;
  float4 v = *(const float4*)(x + (size_t)i * 4);
  ushort4 o;
  o.x = f2bf(v.x); o.y = f2bf(v.y); o.z = f2bf(v.z); o.w = f2bf(v.w);
  *(ushort4*)(xb + (size_t)i * 4) = o;
}

// ---------- W split+transpose: Wt[c][k], c in [0,1152) (8 rels x 128 | root), k in [0,128) ----------
__global__ __launch_bounds__(128) void k_wsplit(const float* __restrict__ W1, const float* __restrict__ Wr1,
                                                ushort* __restrict__ WtH, ushort* __restrict__ WtL) {
  int c = blockIdx.x;          // 0..1151
  int k = threadIdx.x;         // 0..127
  float v;
  if (c < 1024) {
    int r = c >> 7, col = c & 127;
    v = W1[((size_t)r * 128 + k) * 128 + col];
  } else {
    v = Wr1[(size_t)k * 128 + (c - 1024)];
  }
  ushort hi = f2bf(v);
  ushort lo = f2bf(v - bf2f(hi));
  WtH[(size_t)c * 128 + k] = hi;
  WtL[(size_t)c * 128 + k] = lo;
}

// ---------- dense GEMM: Y[N,1152] = xb[N,128] @ Wt^T, bf16 out ----------
// Operand swap: D = mfma(A=Wfrag, B=xbfrag) -> D[row=Y-col][col=node].
// 256 thr = 4 waves; block = 64 nodes; wave w owns C-panel [w*288, w*288+288).
// Per wave: xb frags (4 nf x 4 kc uint4) register-resident; 9 C-chunks of 32 cols
// (cf=2), W hi+lo double-buffered from L2-resident Wt; 576 MFMA/wave; packed
// ushort4 Y stores. Barrier-free, no LDS, all indices static (rule #20).
__global__ __launch_bounds__(256) void k_gemm_dense(
    const ushort* __restrict__ xb,
    const ushort* __restrict__ WtH, const ushort* __restrict__ WtL,
    ushort* __restrict__ Y, int N) {
  int tid = threadIdx.x;
  int w = tid >> 6, lane = tid & 63;
  int n0 = blockIdx.x * 64;
  int wbase = w * 288;

  int frow = lane & 15;
  int fk8 = (lane >> 4) * 8;
  int q4 = (lane >> 4) * 4;

  // node assignment (B-operand cols / D cols)
  int anode[4];
  bool nodeok[4];
  size_t ybase[4];
  #pragma unroll
  for (int nf = 0; nf < 4; nf++) {
    int n = n0 + nf * 16 + frow;
    nodeok[nf] = (n < N);
    anode[nf] = nodeok[nf] ? n : (N - 1);
    ybase[nf] = (size_t)anode[nf] * 1152 + q4;
  }

  // xb fragments: all 4 K-chunks, register-resident (static unroll)
  uint4 xbr[4][4];
  #pragma unroll
  for (int nf = 0; nf < 4; nf++)
    #pragma unroll
    for (int kc = 0; kc < 4; kc++)
      xbr[nf][kc] = *(const uint4*)(xb + (size_t)anode[nf] * 128 + kc * 32 + fk8);

  f32x4 acc[2][4];
  uint4 pw0[2][2], pw1[2][2];  // W frags [cf][plane], double-buffered (static names)

  #define LOADW(P, CB, KC)                                                     \
    {                                                                          \
      _Pragma("unroll")                                                        \
      for (int cf = 0; cf < 2; cf++) {                                         \
        int c_ = (CB) + cf * 16 + frow;                                        \
        P[cf][0] = *(const uint4*)(WtH + (size_t)c_ * 128 + (KC) * 32 + fk8);  \
        P[cf][1] = *(const uint4*)(WtL + (size_t)c_ * 128 + (KC) * 32 + fk8);  \
      }                                                                        \
    }
  #define KSTEP(KC, PWU)                                                       \
    {                                                                          \
      _Pragma("unroll")                                                        \
      for (int cf = 0; cf < 2; cf++) {                                         \
        U128 wh_, wl_;                                                         \
        wh_.u = PWU[cf][0];                                                    \
        wl_.u = PWU[cf][1];                                                    \
        _Pragma("unroll")                                                      \
        for (int nf = 0; nf < 4; nf++) {                                       \
          U128 xv_;                                                            \
          xv_.u = xbr[nf][KC];                                                 \
          acc[cf][nf] = __builtin_amdgcn_mfma_f32_16x16x32_bf16(wh_.s, xv_.s, acc[cf][nf], 0, 0, 0); \
          acc[cf][nf] = __builtin_amdgcn_mfma_f32_16x16x32_bf16(wl_.s, xv_.s, acc[cf][nf], 0, 0, 0); \
        }                                                                      \
      }                                                                        \
    }
  #define CHUNK(CB, NCB, ISLAST)                                               \
    {                                                                          \
      _Pragma("unroll")                                                        \
      for (int cf = 0; cf < 2; cf++)                                           \
        _Pragma("unroll")                                                      \
        for (int nf = 0; nf < 4; nf++) acc[cf][nf] = (f32x4){0.f, 0.f, 0.f, 0.f}; \
      LOADW(pw1, CB, 1);                                                       \
      KSTEP(0, pw0);                                                           \
      LOADW(pw0, CB, 2);                                                       \
      KSTEP(1, pw1);                                                           \
      LOADW(pw1, CB, 3);                                                       \
      KSTEP(2, pw0);                                                           \
      if (!(ISLAST)) { LOADW(pw0, NCB, 0); }                                   \
      KSTEP(3, pw1);                                                           \
      _Pragma("unroll")                                                        \
      for (int cf = 0; cf < 2; cf++)                                           \
        _Pragma("unroll")                                                      \
        for (int nf = 0; nf < 4; nf++) {                                       \
          if (nodeok[nf]) {                                                    \
            ushort4 o_;                                                        \
            o_.x = f2bf(acc[cf][nf][0]);                                       \
            o_.y = f2bf(acc[cf][nf][1]);                                       \
            o_.z = f2bf(acc[cf][nf][2]);                                       \
            o_.w = f2bf(acc[cf][nf][3]);                                       \
            *(ushort4*)(Y + ybase[nf] + (CB) + cf * 16) = o_;                  \
          }                                                                    \
        }                                                                      \
    }

  LOADW(pw0, wbase, 0);

  CHUNK(wbase + 0,   wbase + 32,  0)
  CHUNK(wbase + 32,  wbase + 64,  0)
  CHUNK(wbase + 64,  wbase + 96,  0)
  CHUNK(wbase + 96,  wbase + 128, 0)
  CHUNK(wbase + 128, wbase + 160, 0)
  CHUNK(wbase + 160, wbase + 192, 0)
  CHUNK(wbase + 192, wbase + 224, 0)
  CHUNK(wbase + 224, wbase + 256, 0)
  CHUNK(wbase + 256, 0,           1)

  #undef LOADW
  #undef KSTEP
  #undef CHUNK
}

// ---------- h gather: h[n] = relu(Yroot + b1 + sum_r invc * sum_e Y[src_e, r*128:]) ----------
__global__ __launch_bounds__(256) void k_hgather(const int* __restrict__ offs, const int* __restrict__ hist,
                                                 const int* __restrict__ sorted_src, const ushort* __restrict__ Y,
                                                 const float* __restrict__ b1, float* __restrict__ h, int N) {
  int tid = threadIdx.x;
  int node = blockIdx.x * 4 + (tid >> 6);
  int lane = tid & 63;
  if (node >= N) return;
  int c0 = lane * 2;
  uint vroot = *(const uint*)(Y + (size_t)node * 1152 + 1024 + c0);
  float2 bb = *(const float2*)(b1 + c0);
  float ax = bf2f((ushort)(vroot & 0xffff)) + bb.x;
  float ay = bf2f((ushort)(vroot >> 16)) + bb.y;
  #pragma unroll
  for (int r = 0; r < NR; r++) {
    int seg = node * NR + r;
    int en = offs[seg];
    int cc = hist[seg];
    int st = en - cc;
    float sx = 0.f, sy = 0.f;
    int i = st;
    for (; i + 4 <= en; i += 4) {
      int s0 = sorted_src[i + 0];
      int s1 = sorted_src[i + 1];
      int s2 = sorted_src[i + 2];
      int s3 = sorted_src[i + 3];
      uint v0 = *(const uint*)(Y + (size_t)s0 * 1152 + r * 128 + c0);
      uint v1 = *(const uint*)(Y + (size_t)s1 * 1152 + r * 128 + c0);
      uint v2 = *(const uint*)(Y + (size_t)s2 * 1152 + r * 128 + c0);
      uint v3 = *(const uint*)(Y + (size_t)s3 * 1152 + r * 128 + c0);
      sx += bf2f((ushort)(v0 & 0xffff)) + bf2f((ushort)(v1 & 0xffff)) +
            bf2f((ushort)(v2 & 0xffff)) + bf2f((ushort)(v3 & 0xffff));
      sy += bf2f((ushort)(v0 >> 16)) + bf2f((ushort)(v1 >> 16)) +
            bf2f((ushort)(v2 >> 16)) + bf2f((ushort)(v3 >> 16));
    }
    for (; i < en; i++) {
      int s = sorted_src[i];
      uint v = *(const uint*)(Y + (size_t)s * 1152 + r * 128 + c0);
      sx += bf2f((ushort)(v & 0xffff));
      sy += bf2f((ushort)(v >> 16));
    }
    float inv = 1.f / fmaxf((float)cc, 1.f);
    ax += sx * inv;
    ay += sy * inv;
  }
  float2 o;
  o.x = fmaxf(ax, 0.f);
  o.y = fmaxf(ay, 0.f);
  *(float2*)(h + (size_t)node * DH + c0) = o;
}

// ---------- layer-2 transform: t[n,0:18] = h[n] @ [W2_r(:,0:2)... | Wr2] ----------
__global__ __launch_bounds__(256) void k_l2trans(const float* __restrict__ h,
                                                 const float* __restrict__ W2, const float* __restrict__ Wr2,
                                                 float* __restrict__ t, int N) {
  __shared__ float Wt[18 * 128];
  int tid = threadIdx.x;
  for (int i = tid; i < 2304; i += 256) {
    float v; int oc, d;
    if (i < 2048) { int r = i >> 8, rem = i & 255; d = rem >> 1; int c = rem & 1; oc = r * 2 + c; v = W2[i]; }
    else { int i2 = i - 2048; d = i2 >> 1; int c = i2 & 1; oc = 16 + c; v = Wr2[i2]; }
    Wt[oc * 128 + d] = v;
  }
  __syncthreads();
  int node = blockIdx.x * 4 + (tid >> 6);
  int lane = tid & 63;
  if (node >= N) return;
  float2 hv = *(const float2*)(h + (size_t)node * DH + lane * 2);
  #pragma unroll
  for (int oc = 0; oc < 18; oc++) {
    float2 w = *(const float2*)(Wt + oc * 128 + lane * 2);
    float p = hv.x * w.x + hv.y * w.y;
    p += __shfl_xor(p, 32); p += __shfl_xor(p, 16); p += __shfl_xor(p, 8);
    p += __shfl_xor(p, 4);  p += __shfl_xor(p, 2);  p += __shfl_xor(p, 1);
    if (lane == 0) t[(size_t)node * 18 + oc] = p;
  }
}

// ---------- output: gather tiny t values per segment ----------
__global__ __launch_bounds__(256) void k_out2(const int* __restrict__ offs, const int* __restrict__ hist,
                                              const int* __restrict__ sorted_src, const float* __restrict__ t,
                                              const float* __restrict__ b2, float* __restrict__ out, int N) {
  int n = blockIdx.x * 256 + threadIdx.x;
  if (n >= N) return;
  float o0 = t[(size_t)n * 18 + 16] + b2[0];
  float o1 = t[(size_t)n * 18 + 17] + b2[1];
  #pragma unroll
  for (int r = 0; r < NR; r++) {
    int seg = n * NR + r;
    int en = offs[seg], cc = hist[seg];
    float s0 = 0.f, s1 = 0.f;
    for (int i = en - cc; i < en; i++) {
      int s = sorted_src[i];
      s0 += t[(size_t)s * 18 + r * 2];
      s1 += t[(size_t)s * 18 + r * 2 + 1];
    }
    float inv = 1.f / fmaxf((float)cc, 1.f);
    o0 += s0 * inv;
    o1 += s1 * inv;
  }
  out[(size_t)n * 2 + 0] = o0;
  out[(size_t)n * 2 + 1] = o1;
}

extern "C" void kernel_launch(void* const* d_in, const int* in_sizes, int n_in,
                              void* d_out, int out_size, void* d_ws, size_t ws_size,
                              hipStream_t stream) {
  const float* x   = (const float*)d_in[0];
  const int*   ei  = (const int*)d_in[1];
  const int*   et  = (const int*)d_in[2];
  const float* W1  = (const float*)d_in[3];
  const float* Wr1 = (const float*)d_in[4];
  const float* b1  = (const float*)d_in[5];
  const float* W2  = (const float*)d_in[6];
  const float* Wr2 = (const float*)d_in[7];
  const float* b2  = (const float*)d_in[8];
  float* out = (float*)d_out;

  int E = in_sizes[1] / 2;
  int N = in_sizes[0] / DH;
  int S = N * NR;
  const int* src = ei;
  const int* dst = ei + E;

  // ws layout: ints | xb | WtH WtL | Y (bf16, N*1152) | h (f32) | t
  int* hist       = (int*)d_ws;                  // S
  int* offs       = hist + S;                    // S
  int* blksum     = offs + S;                    // 1024
  int* blkoff     = blksum + 1024;               // 1024
  int* sorted_src = blkoff + 1024;               // E
  size_t int_elems = (size_t)S * 2 + 2048 + E;
  int_elems = (int_elems + 3) & ~(size_t)3;      // 16B align
  ushort* xb  = (ushort*)(hist + int_elems);     // N*128
  ushort* WtH = xb + (size_t)N * DH;             // 1152*128
  ushort* WtL = WtH + 1152 * 128;                // 1152*128
  ushort* Y   = WtL + 1152 * 128;                // N*1152
  size_t ush_elems = (size_t)N * DH + 2 * 1152 * 128 + (size_t)N * 1152;
  ush_elems = (ush_elems + 1) & ~(size_t)1;      // float align
  float* h = (float*)(xb + ush_elems);           // N*128
  float* t = h + (size_t)N * DH;                 // N*18

  hipMemsetAsync(hist, 0, sizeof(int) * (size_t)S, stream);

  k_hist<<<(E + 255) / 256, 256, 0, stream>>>(dst, et, hist, E);

  int NB = (S + 1023) / 1024;
  k_scan_local<<<NB, 256, 0, stream>>>(hist, offs, blksum, S);
  k_scan_blk<<<1, 512, 0, stream>>>(blksum, blkoff, NB);
  k_scan_add<<<NB, 256, 0, stream>>>(offs, blkoff, S);

  k_scatter_idx<<<(E + 255) / 256, 256, 0, stream>>>(src, dst, et, offs, sorted_src, E);

  int total4 = N * DH / 4;
  k_xbf16<<<(total4 + 255) / 256, 256, 0, stream>>>(x, xb, total4);

  k_wsplit<<<1152, 128, 0, stream>>>(W1, Wr1, WtH, WtL);

  k_gemm_dense<<<(N + 63) / 64, 256, 0, stream>>>(xb, WtH, WtL, Y, N);

  k_hgather<<<(N + 3) / 4, 256, 0, stream>>>(offs, hist, sorted_src, Y, b1, h, N);

  k_l2trans<<<(N + 3) / 4, 256, 0, stream>>>(h, W2, Wr2, t, N);

  k_out2<<<(N + 255) / 256, 256, 0, stream>>>(offs, hist, sorted_src, t, b2, out, N);
}